// Round 1
// baseline (241.112 us; speedup 1.0000x reference)
//
#include <hip/hip_runtime.h>

#define NQ   4096
#define NGRP 256
#define LL   64
#define DD   512

// ---------------- group starts: starts[g] = lower_bound(gid, g) ----------------
__global__ __launch_bounds__(256) void k_starts(const int* __restrict__ gid,
                                                int* __restrict__ starts) {
  int g = blockIdx.x * 256 + threadIdx.x;
  if (g > NGRP) return;
  int lo = 0, hi = NQ;
  while (lo < hi) { int mid = (lo + hi) >> 1; if (gid[mid] < g) lo = mid + 1; else hi = mid; }
  starts[g] = lo;
}

// ---------------- b2[d] = sum_j Wk[d][j] * bq[j] ----------------
__global__ __launch_bounds__(256) void k_b2(const float* __restrict__ Wk,
                                            const float* __restrict__ bq,
                                            float* __restrict__ b2) {
  int dd = blockIdx.x * 256 + threadIdx.x;
  if (dd >= DD) return;
  float s = 0.f;
  const float* row = Wk + (size_t)dd * DD;
  for (int j = 0; j < DD; j += 4) {
    float4 w = *(const float4*)&row[j];
    float4 b = *(const float4*)&bq[j];
    s += w.x*b.x + w.y*b.y + w.z*b.z + w.w*b.w;
  }
  b2[dd] = s;
}

// ---------------- generic fp32 tiled GEMM: C[M][N] = A[M][K] @ B (+bias) ------
// BT=true: B is given row-major [N][K] (compute A @ B^T). BT=false: B is [K][N].
template<int BM, int BN, int BK, bool BT, bool BIAS>
__global__ __launch_bounds__(256) void gemm_f32(
    const float* __restrict__ A, const float* __restrict__ B,
    const float* __restrict__ bias, float* __restrict__ C,
    int M, int N, int K) {
  constexpr int MT = BM / 16;
  constexpr int NT = BN / 16;
  __shared__ __align__(16) float As[BK][BM];
  __shared__ __align__(16) float Bs[BK][BN];
  int t = threadIdx.x;
  int tx = t & 15, ty = t >> 4;
  int m0 = blockIdx.y * BM, n0 = blockIdx.x * BN;
  float acc[MT][NT];
  #pragma unroll
  for (int i = 0; i < MT; ++i)
    #pragma unroll
    for (int j = 0; j < NT; ++j) acc[i][j] = 0.f;

  for (int k0 = 0; k0 < K; k0 += BK) {
    __syncthreads();
    // stage A tile transposed: As[k][m]
    #pragma unroll
    for (int idx = t; idx < BM*BK/4; idx += 256) {
      int r = idx / (BK/4), c4 = idx % (BK/4);
      float4 vA = *(const float4*)&A[(size_t)(m0 + r)*K + k0 + c4*4];
      As[c4*4+0][r] = vA.x; As[c4*4+1][r] = vA.y;
      As[c4*4+2][r] = vA.z; As[c4*4+3][r] = vA.w;
    }
    if (BT) {
      // B[n][k] tile -> Bs[k][n] (transpose on store)
      #pragma unroll
      for (int idx = t; idx < BN*BK/4; idx += 256) {
        int r = idx / (BK/4), c4 = idx % (BK/4);
        float4 vB = *(const float4*)&B[(size_t)(n0 + r)*K + k0 + c4*4];
        Bs[c4*4+0][r] = vB.x; Bs[c4*4+1][r] = vB.y;
        Bs[c4*4+2][r] = vB.z; Bs[c4*4+3][r] = vB.w;
      }
    } else {
      // B[k][n] tile -> Bs[k][n] natural
      #pragma unroll
      for (int idx = t; idx < BK*BN/4; idx += 256) {
        int r = idx / (BN/4), c4 = idx % (BN/4);
        float4 vB = *(const float4*)&B[(size_t)(k0 + r)*N + n0 + c4*4];
        *(float4*)&Bs[r][c4*4] = vB;
      }
    }
    __syncthreads();
    #pragma unroll
    for (int kk = 0; kk < BK; ++kk) {
      float a[MT], b[NT];
      #pragma unroll
      for (int i = 0; i < MT; ++i) a[i] = As[kk][ty*MT + i];
      #pragma unroll
      for (int j = 0; j < NT; ++j) b[j] = Bs[kk][tx*NT + j];
      #pragma unroll
      for (int i = 0; i < MT; ++i)
        #pragma unroll
        for (int j = 0; j < NT; ++j) acc[i][j] += a[i]*b[j];
    }
  }
  #pragma unroll
  for (int i = 0; i < MT; ++i) {
    int mm = m0 + ty*MT + i;
    #pragma unroll
    for (int j = 0; j < NT; ++j) {
      float cval = acc[i][j];
      if (BIAS) cval += bias[n0 + tx*NT + j];
      C[(size_t)mm*N + n0 + tx*NT + j] = cval;
    }
  }
}

// ---------------- fused grouped attention ----------------
// One block pair per group (blockIdx.x>>1 = g, &1 = chunk parity).
// Per 16-query chunk: qt chunk -> LDS; QK with per-thread (2l x 16q) register
// blocking; partial-d reduce via shfl+LDS; 16-lane-group softmax; PV with
// (8q x 4d) register blocking, coalesced v reads.
__global__ __launch_bounds__(256) void k_attn(
    const float* __restrict__ qt, const float* __restrict__ kk_,
    const float* __restrict__ vv_, const float* __restrict__ msk,
    const int* __restrict__ starts, float* __restrict__ out) {
  int g = blockIdx.x >> 1;
  int half = blockIdx.x & 1;
  int t = threadIdx.x;
  int s0 = starts[g], s1 = starts[g + 1];
  int cnt = s1 - s0;
  if (cnt <= half * 16) return;

  __shared__ __align__(16) float qt_lds[16][DD];     // 32 KB
  __shared__ __align__(16) float sred[4][16][LL];    // 16 KB
  __shared__ __align__(16) float a_lds[LL][16];      // 4 KB
  __shared__ float bias_lds[LL];

  if (t < LL) {
    float mv = msk[g * LL + t];
    bias_lds[t] = __expf(50.0f * (1.0f - mv)) - 1.0f;
  }

  for (int cs = s0 + half * 16; cs < s1; cs += 32) {
    int qc = min(16, s1 - cs);
    __syncthreads();
    // ---- stage qt chunk (zero-pad past qc) ----
    #pragma unroll
    for (int r = 0; r < 8; ++r) {
      int idx = r * 256 + t;
      int q = idx >> 7, d4 = idx & 127;
      float4 val = make_float4(0.f, 0.f, 0.f, 0.f);
      if (q < qc) val = *(const float4*)&qt[(size_t)(cs + q) * DD + d4 * 4];
      *(float4*)&qt_lds[q][d4 * 4] = val;
    }
    __syncthreads();
    // ---- QK: thread = (l2 = t&31 -> rows 2*l2,2*l2+1; dc = t>>5 -> d window) ----
    {
      int l2 = t & 31, dc = t >> 5;
      const float* kb0 = kk_ + ((size_t)g * LL + l2 * 2) * DD + dc * 64;
      const float* kb1 = kb0 + DD;
      float acc0[16], acc1[16];
      #pragma unroll
      for (int q = 0; q < 16; ++q) { acc0[q] = 0.f; acc1[q] = 0.f; }
      #pragma unroll
      for (int d4 = 0; d4 < 16; ++d4) {
        float4 kv0 = *(const float4*)&kb0[d4 * 4];
        float4 kv1 = *(const float4*)&kb1[d4 * 4];
        #pragma unroll
        for (int q = 0; q < 16; ++q) {
          float4 qv = *(const float4*)&qt_lds[q][dc * 64 + d4 * 4];
          acc0[q] += kv0.x*qv.x + kv0.y*qv.y + kv0.z*qv.z + kv0.w*qv.w;
          acc1[q] += kv1.x*qv.x + kv1.y*qv.y + kv1.z*qv.z + kv1.w*qv.w;
        }
      }
      // fold dc pairs (lanes l and l+32 of each wave) via shfl, halve LDS traffic
      #pragma unroll
      for (int q = 0; q < 16; ++q) {
        acc0[q] += __shfl_xor(acc0[q], 32);
        acc1[q] += __shfl_xor(acc1[q], 32);
      }
      if ((t & 32) == 0) {
        int w = t >> 6;  // dc-pair index 0..3
        #pragma unroll
        for (int q = 0; q < 16; ++q) {
          sred[w][q][l2 * 2]     = acc0[q];
          sred[w][q][l2 * 2 + 1] = acc1[q];
        }
      }
    }
    __syncthreads();
    // ---- reduce partial-d sums, scale, mask bias ----
    #pragma unroll
    for (int r = 0; r < 4; ++r) {
      int idx = r * 256 + t;
      int q = idx >> 6, l = idx & 63;
      float ssum = 0.f;
      #pragma unroll
      for (int dc = 0; dc < 4; ++dc) ssum += sred[dc][q][l];
      a_lds[l][q] = ssum * 0.044194173824159216f - bias_lds[l];
    }
    __syncthreads();
    // ---- softmax over l: 16 lanes per query ----
    {
      int q = t >> 4, i = t & 15;
      float sv0 = a_lds[i][q], sv1 = a_lds[i + 16][q];
      float sv2 = a_lds[i + 32][q], sv3 = a_lds[i + 48][q];
      float mx = fmaxf(fmaxf(sv0, sv1), fmaxf(sv2, sv3));
      #pragma unroll
      for (int off = 1; off < 16; off <<= 1) mx = fmaxf(mx, __shfl_xor(mx, off, 16));
      float e0 = __expf(sv0 - mx), e1 = __expf(sv1 - mx);
      float e2 = __expf(sv2 - mx), e3 = __expf(sv3 - mx);
      float sum = e0 + e1 + e2 + e3;
      #pragma unroll
      for (int off = 1; off < 16; off <<= 1) sum += __shfl_xor(sum, off, 16);
      float inv = 1.0f / sum;
      a_lds[i][q] = e0 * inv; a_lds[i + 16][q] = e1 * inv;
      a_lds[i + 32][q] = e2 * inv; a_lds[i + 48][q] = e3 * inv;
    }
    __syncthreads();
    // ---- PV: thread = (d4 = t&127 -> 4 d's; qh = t>>7 -> 8 queries) ----
    {
      int d4 = t & 127, qh = t >> 7;
      float o[8][4];
      #pragma unroll
      for (int qi = 0; qi < 8; ++qi) { o[qi][0]=0.f; o[qi][1]=0.f; o[qi][2]=0.f; o[qi][3]=0.f; }
      const float* vb = vv_ + (size_t)g * LL * DD + d4 * 4;
      #pragma unroll 4
      for (int l = 0; l < LL; ++l) {
        float4 vv = *(const float4*)&vb[(size_t)l * DD];
        #pragma unroll
        for (int jj = 0; jj < 2; ++jj) {
          float4 aa = *(const float4*)&a_lds[l][qh * 8 + jj * 4];
          float av[4] = {aa.x, aa.y, aa.z, aa.w};
          #pragma unroll
          for (int u = 0; u < 4; ++u) {
            int qi = jj * 4 + u;
            o[qi][0] += av[u] * vv.x; o[qi][1] += av[u] * vv.y;
            o[qi][2] += av[u] * vv.z; o[qi][3] += av[u] * vv.w;
          }
        }
      }
      #pragma unroll
      for (int qi = 0; qi < 8; ++qi) {
        int q = qh * 8 + qi;
        if (q < qc) {
          float4 ov = make_float4(o[qi][0], o[qi][1], o[qi][2], o[qi][3]);
          *(float4*)&out[(size_t)(cs + q) * DD + d4 * 4] = ov;
        }
      }
    }
  }
}

extern "C" void kernel_launch(void* const* d_in, const int* in_sizes, int n_in,
                              void* d_out, int out_size, void* d_ws, size_t ws_size,
                              hipStream_t stream) {
  const float* q_in = (const float*)d_in[0];
  const float* k_in = (const float*)d_in[1];
  const float* v_in = (const float*)d_in[2];
  const float* m_in = (const float*)d_in[3];
  const int*   gid  = (const int*)d_in[4];
  const float* Wq   = (const float*)d_in[5];
  const float* bq   = (const float*)d_in[6];
  const float* Wk   = (const float*)d_in[7];
  // d_in[8] = bk: adds a per-query constant to all scores -> cancels in softmax.
  float* out = (float*)d_out;

  // workspace carve (floats): W2[1024*512] | b2[512] | starts[512 ints] | qt[4096*512]
  float* W2 = (float*)d_ws;
  float* b2 = W2 + 1024 * 512;
  int* starts = (int*)(b2 + 512);
  float* qt = (float*)(starts + 512);

  k_starts<<<2, 256, 0, stream>>>(gid, starts);
  k_b2<<<2, 256, 0, stream>>>(Wk, bq, b2);
  // W2 = Wq @ Wk^T : M=1024, N=512, K=512
  gemm_f32<32, 64, 32, true, false><<<dim3(512 / 64, 1024 / 32), 256, 0, stream>>>(
      Wq, Wk, nullptr, W2, 1024, 512, 512);
  // qt = q @ W2 + b2 : M=4096, N=512, K=1024
  gemm_f32<64, 64, 32, false, true><<<dim3(512 / 64, 4096 / 64), 256, 0, stream>>>(
      q_in, W2, b2, qt, 4096, 512, 1024);
  // fused grouped attention
  k_attn<<<512, 256, 0, stream>>>(qt, k_in, v_in, m_in, starts, out);
}

// Round 2
// 199.012 us; speedup vs baseline: 1.2115x; 1.2115x over previous
//
#include <hip/hip_runtime.h>

#define NQ   4096
#define NGRP 256
#define LL   64
#define DD   512

// ---------------- group starts: starts[g] = lower_bound(gid, g) ----------------
__global__ __launch_bounds__(256) void k_starts(const int* __restrict__ gid,
                                                int* __restrict__ starts) {
  int g = blockIdx.x * 256 + threadIdx.x;
  if (g > NGRP) return;
  int lo = 0, hi = NQ;
  while (lo < hi) { int mid = (lo + hi) >> 1; if (gid[mid] < g) lo = mid + 1; else hi = mid; }
  starts[g] = lo;
}

// ---------------- b2[d] = sum_j Wk[d][j] * bq[j] ----------------
__global__ __launch_bounds__(256) void k_b2(const float* __restrict__ Wk,
                                            const float* __restrict__ bq,
                                            float* __restrict__ b2) {
  int dd = blockIdx.x * 256 + threadIdx.x;
  if (dd >= DD) return;
  float s = 0.f;
  const float* row = Wk + (size_t)dd * DD;
  for (int j = 0; j < DD; j += 4) {
    float4 w = *(const float4*)&row[j];
    float4 b = *(const float4*)&bq[j];
    s += w.x*b.x + w.y*b.y + w.z*b.z + w.w*b.w;
  }
  b2[dd] = s;
}

// ---------------- generic fp32 tiled GEMM: C[M][N] = A[M][K] @ B (+bias) ------
// BT=true: B is given row-major [N][K] (compute A @ B^T). BT=false: B is [K][N].
// Fragment loads are vectorized (float4/float2) -> 2 ds_read_b128 per 16 FMA.
template<int BM, int BN, int BK, bool BT, bool BIAS>
__global__ __launch_bounds__(256) void gemm_f32(
    const float* __restrict__ A, const float* __restrict__ B,
    const float* __restrict__ bias, float* __restrict__ C,
    int M, int N, int K) {
  constexpr int MT = BM / 16;
  constexpr int NT = BN / 16;
  __shared__ __align__(16) float As[BK][BM];
  __shared__ __align__(16) float Bs[BK][BN];
  int t = threadIdx.x;
  int tx = t & 15, ty = t >> 4;
  int m0 = blockIdx.y * BM, n0 = blockIdx.x * BN;
  float acc[MT][NT];
  #pragma unroll
  for (int i = 0; i < MT; ++i)
    #pragma unroll
    for (int j = 0; j < NT; ++j) acc[i][j] = 0.f;

  for (int k0 = 0; k0 < K; k0 += BK) {
    __syncthreads();
    // stage A tile transposed: As[k][m]
    #pragma unroll
    for (int idx = t; idx < BM*BK/4; idx += 256) {
      int r = idx / (BK/4), c4 = idx % (BK/4);
      float4 vA = *(const float4*)&A[(size_t)(m0 + r)*K + k0 + c4*4];
      As[c4*4+0][r] = vA.x; As[c4*4+1][r] = vA.y;
      As[c4*4+2][r] = vA.z; As[c4*4+3][r] = vA.w;
    }
    if (BT) {
      // B[n][k] tile -> Bs[k][n] (transpose on store)
      #pragma unroll
      for (int idx = t; idx < BN*BK/4; idx += 256) {
        int r = idx / (BK/4), c4 = idx % (BK/4);
        float4 vB = *(const float4*)&B[(size_t)(n0 + r)*K + k0 + c4*4];
        Bs[c4*4+0][r] = vB.x; Bs[c4*4+1][r] = vB.y;
        Bs[c4*4+2][r] = vB.z; Bs[c4*4+3][r] = vB.w;
      }
    } else {
      // B[k][n] tile -> Bs[k][n] natural
      #pragma unroll
      for (int idx = t; idx < BK*BN/4; idx += 256) {
        int r = idx / (BN/4), c4 = idx % (BN/4);
        float4 vB = *(const float4*)&B[(size_t)(k0 + r)*N + n0 + c4*4];
        *(float4*)&Bs[r][c4*4] = vB;
      }
    }
    __syncthreads();
    #pragma unroll
    for (int kk = 0; kk < BK; ++kk) {
      float a[MT], b[NT];
      if constexpr (MT == 4) {
        float4 va = *(const float4*)&As[kk][ty*4];
        a[0]=va.x; a[1]=va.y; a[2]=va.z; a[3]=va.w;
      } else if constexpr (MT == 2) {
        float2 va = *(const float2*)&As[kk][ty*2];
        a[0]=va.x; a[1]=va.y;
      } else {
        #pragma unroll
        for (int i = 0; i < MT; ++i) a[i] = As[kk][ty*MT + i];
      }
      if constexpr (NT == 4) {
        float4 vb = *(const float4*)&Bs[kk][tx*4];
        b[0]=vb.x; b[1]=vb.y; b[2]=vb.z; b[3]=vb.w;
      } else {
        #pragma unroll
        for (int j = 0; j < NT; ++j) b[j] = Bs[kk][tx*NT + j];
      }
      #pragma unroll
      for (int i = 0; i < MT; ++i)
        #pragma unroll
        for (int j = 0; j < NT; ++j) acc[i][j] += a[i]*b[j];
    }
  }
  #pragma unroll
  for (int i = 0; i < MT; ++i) {
    int mm = m0 + ty*MT + i;
    #pragma unroll
    for (int j = 0; j < NT; ++j) {
      float cval = acc[i][j];
      if (BIAS) cval += bias[n0 + tx*NT + j];
      C[(size_t)mm*N + n0 + tx*NT + j] = cval;
    }
  }
}

// ---------------- scores + softmax: a[n][l] ----------------
// Block pair per group (blockIdx.x>>1 = g, &1 = parity). Per 16-query chunk:
// qt chunk -> LDS; QK with (2l x 16q) register blocking; shfl+LDS d-reduce;
// 16-lane-group softmax; write a to global.
__global__ __launch_bounds__(256) void k_scores(
    const float* __restrict__ qt, const float* __restrict__ kk_,
    const float* __restrict__ msk, const int* __restrict__ starts,
    float* __restrict__ a_out) {
  int g = blockIdx.x >> 1;
  int half = blockIdx.x & 1;
  int t = threadIdx.x;
  int s0 = starts[g], s1 = starts[g + 1];
  if (s1 - s0 <= half * 16) return;

  __shared__ __align__(16) float qt_lds[16][DD];     // 32 KB
  __shared__ __align__(16) float sred[4][16][LL];    // 16 KB
  __shared__ __align__(16) float s_lds[LL][16];      // 4 KB
  __shared__ float bias_lds[LL];

  if (t < LL) {
    float mv = msk[g * LL + t];
    bias_lds[t] = __expf(50.0f * (1.0f - mv)) - 1.0f;
  }

  for (int cs = s0 + half * 16; cs < s1; cs += 32) {
    int qc = min(16, s1 - cs);
    __syncthreads();
    // ---- stage qt chunk (zero-pad past qc) ----
    #pragma unroll
    for (int r = 0; r < 8; ++r) {
      int idx = r * 256 + t;
      int q = idx >> 7, d4 = idx & 127;
      float4 val = make_float4(0.f, 0.f, 0.f, 0.f);
      if (q < qc) val = *(const float4*)&qt[(size_t)(cs + q) * DD + d4 * 4];
      *(float4*)&qt_lds[q][d4 * 4] = val;
    }
    __syncthreads();
    // ---- QK: thread = (l2 = t&31 -> rows 2*l2,2*l2+1; dc = t>>5 -> d window) ----
    {
      int l2 = t & 31, dc = t >> 5;
      const float* kb0 = kk_ + ((size_t)g * LL + l2 * 2) * DD + dc * 64;
      const float* kb1 = kb0 + DD;
      float acc0[16], acc1[16];
      #pragma unroll
      for (int q = 0; q < 16; ++q) { acc0[q] = 0.f; acc1[q] = 0.f; }
      #pragma unroll
      for (int d4 = 0; d4 < 16; ++d4) {
        float4 kv0 = *(const float4*)&kb0[d4 * 4];
        float4 kv1 = *(const float4*)&kb1[d4 * 4];
        #pragma unroll
        for (int q = 0; q < 16; ++q) {
          float4 qv = *(const float4*)&qt_lds[q][dc * 64 + d4 * 4];
          acc0[q] += kv0.x*qv.x + kv0.y*qv.y + kv0.z*qv.z + kv0.w*qv.w;
          acc1[q] += kv1.x*qv.x + kv1.y*qv.y + kv1.z*qv.z + kv1.w*qv.w;
        }
      }
      #pragma unroll
      for (int q = 0; q < 16; ++q) {
        acc0[q] += __shfl_xor(acc0[q], 32);
        acc1[q] += __shfl_xor(acc1[q], 32);
      }
      if ((t & 32) == 0) {
        int w = t >> 6;  // dc-pair index 0..3
        #pragma unroll
        for (int q = 0; q < 16; ++q) {
          sred[w][q][l2 * 2]     = acc0[q];
          sred[w][q][l2 * 2 + 1] = acc1[q];
        }
      }
    }
    __syncthreads();
    // ---- reduce partial-d sums, scale, mask bias ----
    #pragma unroll
    for (int r = 0; r < 4; ++r) {
      int idx = r * 256 + t;
      int q = idx >> 6, l = idx & 63;
      float ssum = 0.f;
      #pragma unroll
      for (int dc = 0; dc < 4; ++dc) ssum += sred[dc][q][l];
      s_lds[l][q] = ssum * 0.044194173824159216f - bias_lds[l];
    }
    __syncthreads();
    // ---- softmax over l: 16 lanes per query; write a to global ----
    {
      int q = t >> 4, i = t & 15;
      float sv0 = s_lds[i][q], sv1 = s_lds[i + 16][q];
      float sv2 = s_lds[i + 32][q], sv3 = s_lds[i + 48][q];
      float mx = fmaxf(fmaxf(sv0, sv1), fmaxf(sv2, sv3));
      #pragma unroll
      for (int off = 1; off < 16; off <<= 1) mx = fmaxf(mx, __shfl_xor(mx, off, 16));
      float e0 = __expf(sv0 - mx), e1 = __expf(sv1 - mx);
      float e2 = __expf(sv2 - mx), e3 = __expf(sv3 - mx);
      float sum = e0 + e1 + e2 + e3;
      #pragma unroll
      for (int off = 1; off < 16; off <<= 1) sum += __shfl_xor(sum, off, 16);
      float inv = 1.0f / sum;
      if (q < qc) {
        float* ap = a_out + (size_t)(cs + q) * LL;
        ap[i]      = e0 * inv;
        ap[i + 16] = e1 * inv;
        ap[i + 32] = e2 * inv;
        ap[i + 48] = e3 * inv;
      }
    }
  }
}

// ---------------- PV: out[n][d] = sum_l a[n][l] * v[g][l][d] ----------------
// Grid: 256 groups x 2 parity x 2 d-halves = 1024 blocks, 256 threads.
// Thread = (d4 = t&63 -> 4 d's; qh = t>>6 -> 4 queries). Tiny LDS -> high occ.
__global__ __launch_bounds__(256) void k_pv(
    const float* __restrict__ a_in, const float* __restrict__ vv_,
    const int* __restrict__ starts, float* __restrict__ out) {
  int g = blockIdx.x >> 2;
  int half = (blockIdx.x >> 1) & 1;
  int dh = blockIdx.x & 1;
  int t = threadIdx.x;
  int s0 = starts[g], s1 = starts[g + 1];
  if (s1 - s0 <= half * 16) return;

  __shared__ __align__(16) float al[LL][17];  // transposed a chunk, padded

  int d4 = t & 63, qh = t >> 6;
  const float* vb = vv_ + (size_t)g * LL * DD + dh * 256 + d4 * 4;

  for (int cs = s0 + half * 16; cs < s1; cs += 32) {
    int qc = min(16, s1 - cs);
    __syncthreads();
    // stage a chunk transposed: al[l][q]
    {
      int q = t >> 4, l4 = t & 15;
      int row = min(cs + q, NQ - 1);
      float4 av = *(const float4*)&a_in[(size_t)row * LL + l4 * 4];
      al[l4 * 4 + 0][q] = av.x; al[l4 * 4 + 1][q] = av.y;
      al[l4 * 4 + 2][q] = av.z; al[l4 * 4 + 3][q] = av.w;
    }
    __syncthreads();
    float o[4][4];
    #pragma unroll
    for (int u = 0; u < 4; ++u) { o[u][0]=0.f; o[u][1]=0.f; o[u][2]=0.f; o[u][3]=0.f; }
    #pragma unroll 8
    for (int l = 0; l < LL; ++l) {
      float4 vv = *(const float4*)&vb[(size_t)l * DD];
      float4 aa = *(const float4*)&al[l][qh * 4];
      float av[4] = {aa.x, aa.y, aa.z, aa.w};
      #pragma unroll
      for (int u = 0; u < 4; ++u) {
        o[u][0] += av[u] * vv.x; o[u][1] += av[u] * vv.y;
        o[u][2] += av[u] * vv.z; o[u][3] += av[u] * vv.w;
      }
    }
    #pragma unroll
    for (int u = 0; u < 4; ++u) {
      int q = qh * 4 + u;
      if (q < qc) {
        float4 ov = make_float4(o[u][0], o[u][1], o[u][2], o[u][3]);
        *(float4*)&out[(size_t)(cs + q) * DD + dh * 256 + d4 * 4] = ov;
      }
    }
  }
}

extern "C" void kernel_launch(void* const* d_in, const int* in_sizes, int n_in,
                              void* d_out, int out_size, void* d_ws, size_t ws_size,
                              hipStream_t stream) {
  const float* q_in = (const float*)d_in[0];
  const float* k_in = (const float*)d_in[1];
  const float* v_in = (const float*)d_in[2];
  const float* m_in = (const float*)d_in[3];
  const int*   gid  = (const int*)d_in[4];
  const float* Wq   = (const float*)d_in[5];
  const float* bq   = (const float*)d_in[6];
  const float* Wk   = (const float*)d_in[7];
  // d_in[8] = bk: per-query constant on all scores -> cancels in softmax.
  float* out = (float*)d_out;

  // ws carve (floats): W2[1024*512] | b2[512] | starts[512 ints] | qt[4096*512]
  // a[4096*64] aliases W2 (W2 is dead after the qt GEMM).
  float* W2 = (float*)d_ws;
  float* b2 = W2 + 1024 * 512;
  int* starts = (int*)(b2 + 512);
  float* qt = (float*)(starts + 512);
  float* a  = W2;  // alias: 1 MB <= 2 MB region

  k_starts<<<2, 256, 0, stream>>>(gid, starts);
  k_b2<<<2, 256, 0, stream>>>(Wk, bq, b2);
  // W2 = Wq @ Wk^T : M=1024, N=512, K=512
  gemm_f32<32, 64, 32, true, false><<<dim3(512 / 64, 1024 / 32), 256, 0, stream>>>(
      Wq, Wk, nullptr, W2, 1024, 512, 512);
  // qt = q @ W2 + b2 : M=4096, N=512, K=1024
  gemm_f32<64, 64, 32, false, true><<<dim3(512 / 64, 4096 / 64), 256, 0, stream>>>(
      q_in, W2, b2, qt, 4096, 512, 1024);
  // scores + softmax -> a
  k_scores<<<512, 256, 0, stream>>>(qt, k_in, m_in, starts, a);
  // out = a @ v (grouped)
  k_pv<<<1024, 256, 0, stream>>>(a, v_in, starts, out);
}

// Round 3
// 153.870 us; speedup vs baseline: 1.5670x; 1.2934x over previous
//
#include <hip/hip_runtime.h>

#define NQ   4096
#define NGRP 256
#define LL   64
#define DD   512

typedef __attribute__((ext_vector_type(8))) short short8v;
typedef __attribute__((ext_vector_type(4))) float f32x4;

// float -> bf16 bits, round-to-nearest-even
static __device__ __forceinline__ unsigned short f2bf(float f) {
  union { float f; unsigned u; } x{f};
  unsigned r = x.u + 0x7fffu + ((x.u >> 16) & 1u);
  return (unsigned short)(r >> 16);
}
static __device__ __forceinline__ float bf2f(unsigned short h) {
  union { unsigned u; float f; } x{(unsigned)h << 16};
  return x.f;
}

// ---------------- group starts: starts[g] = lower_bound(gid, g) ----------------
__global__ __launch_bounds__(256) void k_starts(const int* __restrict__ gid,
                                                int* __restrict__ starts) {
  int g = blockIdx.x * 256 + threadIdx.x;
  if (g > NGRP) return;
  int lo = 0, hi = NQ;
  while (lo < hi) { int mid = (lo + hi) >> 1; if (gid[mid] < g) lo = mid + 1; else hi = mid; }
  starts[g] = lo;
}

// ---------------- b2[d] = sum_j Wk[d][j] * bq[j] ----------------
__global__ __launch_bounds__(256) void k_b2(const float* __restrict__ Wk,
                                            const float* __restrict__ bq,
                                            float* __restrict__ b2) {
  int dd = blockIdx.x * 256 + threadIdx.x;
  if (dd >= DD) return;
  float s = 0.f;
  const float* row = Wk + (size_t)dd * DD;
  for (int j = 0; j < DD; j += 4) {
    float4 w = *(const float4*)&row[j];
    float4 b = *(const float4*)&bq[j];
    s += w.x*b.x + w.y*b.y + w.z*b.z + w.w*b.w;
  }
  b2[dd] = s;
}

// ---------------- W2T = Wk @ Wq^T, output split bf16 hi/lo ----------------
// M=512 (rows n), N=1024 (cols m), K=512. A=Wk [512][512], B=Wq [1024][512] (BT).
// BM=32, BN=64, BK=32; grid (16,16), 256 threads. fp32 inner (validated R1/R2),
// epilogue: hi = bf16(c), lo = bf16(c - hi).
__global__ __launch_bounds__(256) void gemm_w2t(
    const float* __restrict__ Wk, const float* __restrict__ Wq,
    unsigned short* __restrict__ w2t_h, unsigned short* __restrict__ w2t_l) {
  constexpr int BM = 32, BN = 64, BK = 32, M_ = 512, N_ = 1024, K_ = 512;
  constexpr int MT = 2, NT = 4;
  __shared__ __align__(16) float As[BK][BM];
  __shared__ __align__(16) float Bs[BK][BN];
  int t = threadIdx.x;
  int tx = t & 15, ty = t >> 4;
  int m0 = blockIdx.y * BM, n0 = blockIdx.x * BN;
  float acc[MT][NT];
  #pragma unroll
  for (int i = 0; i < MT; ++i)
    #pragma unroll
    for (int j = 0; j < NT; ++j) acc[i][j] = 0.f;

  for (int k0 = 0; k0 < K_; k0 += BK) {
    __syncthreads();
    #pragma unroll
    for (int idx = t; idx < BM*BK/4; idx += 256) {
      int r = idx / (BK/4), c4 = idx % (BK/4);
      float4 vA = *(const float4*)&Wk[(size_t)(m0 + r)*K_ + k0 + c4*4];
      As[c4*4+0][r] = vA.x; As[c4*4+1][r] = vA.y;
      As[c4*4+2][r] = vA.z; As[c4*4+3][r] = vA.w;
    }
    #pragma unroll
    for (int idx = t; idx < BN*BK/4; idx += 256) {
      int r = idx / (BK/4), c4 = idx % (BK/4);
      float4 vB = *(const float4*)&Wq[(size_t)(n0 + r)*K_ + k0 + c4*4];
      Bs[c4*4+0][r] = vB.x; Bs[c4*4+1][r] = vB.y;
      Bs[c4*4+2][r] = vB.z; Bs[c4*4+3][r] = vB.w;
    }
    __syncthreads();
    #pragma unroll
    for (int kk = 0; kk < BK; ++kk) {
      float2 va = *(const float2*)&As[kk][ty*2];
      float4 vb = *(const float4*)&Bs[kk][tx*4];
      float a0 = va.x, a1 = va.y;
      acc[0][0] += a0*vb.x; acc[0][1] += a0*vb.y; acc[0][2] += a0*vb.z; acc[0][3] += a0*vb.w;
      acc[1][0] += a1*vb.x; acc[1][1] += a1*vb.y; acc[1][2] += a1*vb.z; acc[1][3] += a1*vb.w;
    }
  }
  #pragma unroll
  for (int i = 0; i < MT; ++i) {
    int mm = m0 + ty*MT + i;
    #pragma unroll
    for (int j = 0; j < NT; ++j) {
      float c = acc[i][j];
      unsigned short hi = f2bf(c);
      unsigned short lo = f2bf(c - bf2f(hi));
      size_t off = (size_t)mm * N_ + n0 + tx*NT + j;
      w2t_h[off] = hi;
      w2t_l[off] = lo;
    }
  }
}

// ---------------- qt = q @ W2 + b2 via split-bf16 MFMA ----------------
// M=4096, N=512, K=1024. A = bf16(q) on the fly; B = W2T hi/lo bf16 [512][1024].
// acc += A*Bhi + A*Blo. BM=128, BN=64, BK=64; 256 threads = 4 waves (2x2).
// LDS tiles XOR-slot-swizzled: f4slot(r,s) = r*8 + (s ^ (r&7)).
__global__ __launch_bounds__(256) void gemm_qt_mfma(
    const float* __restrict__ q_in,               // [4096][1024]
    const unsigned short* __restrict__ w2t_h,     // [512][1024]
    const unsigned short* __restrict__ w2t_l,
    const float* __restrict__ b2,                 // [512]
    float* __restrict__ qt) {                     // [4096][512]
  __shared__ __align__(16) unsigned short As[128 * 64];  // 16 KB
  __shared__ __align__(16) unsigned short Bh[64 * 64];   // 8 KB
  __shared__ __align__(16) unsigned short Bl[64 * 64];   // 8 KB
  int t = threadIdx.x;
  int lane = t & 63, wid = t >> 6;
  int wm = wid >> 1, wn = wid & 1;
  int n0 = blockIdx.x * 64, m0 = blockIdx.y * 128;

  f32x4 acc[4][2];
  #pragma unroll
  for (int i = 0; i < 4; ++i)
    #pragma unroll
    for (int j = 0; j < 2; ++j) acc[i][j] = (f32x4){0.f, 0.f, 0.f, 0.f};

  for (int k0 = 0; k0 < 1024; k0 += 64) {
    __syncthreads();
    // ---- stage A: 128 rows x 8 slots; convert fp32 -> bf16 in-flight ----
    #pragma unroll
    for (int i = 0; i < 4; ++i) {
      int idx = i * 256 + t;
      int r = idx >> 3, s = idx & 7;
      const float* src = q_in + (size_t)(m0 + r) * 1024 + k0 + s * 8;
      float4 f0 = *(const float4*)src;
      float4 f1 = *(const float4*)(src + 4);
      uint4 pk;
      pk.x = (unsigned)f2bf(f0.x) | ((unsigned)f2bf(f0.y) << 16);
      pk.y = (unsigned)f2bf(f0.z) | ((unsigned)f2bf(f0.w) << 16);
      pk.z = (unsigned)f2bf(f1.x) | ((unsigned)f2bf(f1.y) << 16);
      pk.w = (unsigned)f2bf(f1.z) | ((unsigned)f2bf(f1.w) << 16);
      ((uint4*)As)[r * 8 + (s ^ (r & 7))] = pk;
    }
    // ---- stage B hi/lo: 64 rows x 8 slots each ----
    #pragma unroll
    for (int i = 0; i < 2; ++i) {
      int idx = i * 256 + t;
      int r = idx >> 3, s = idx & 7;
      int dst = r * 8 + (s ^ (r & 7));
      ((uint4*)Bh)[dst] = *(const uint4*)(w2t_h + (size_t)(n0 + r) * 1024 + k0 + s * 8);
      ((uint4*)Bl)[dst] = *(const uint4*)(w2t_l + (size_t)(n0 + r) * 1024 + k0 + s * 8);
    }
    __syncthreads();
    // ---- MFMA: 2 K-substeps of 32 ----
    #pragma unroll
    for (int kk = 0; kk < 2; ++kk) {
      short8v aF[4], bHF[2], bLF[2];
      int sl = kk * 4 + (lane >> 4);
      #pragma unroll
      for (int fm = 0; fm < 4; ++fm) {
        int r = wm * 64 + fm * 16 + (lane & 15);
        aF[fm] = *(const short8v*)(As + (r * 8 + (sl ^ (r & 7))) * 8);
      }
      #pragma unroll
      for (int fn = 0; fn < 2; ++fn) {
        int r = wn * 32 + fn * 16 + (lane & 15);
        int off = (r * 8 + (sl ^ (r & 7))) * 8;
        bHF[fn] = *(const short8v*)(Bh + off);
        bLF[fn] = *(const short8v*)(Bl + off);
      }
      #pragma unroll
      for (int fm = 0; fm < 4; ++fm)
        #pragma unroll
        for (int fn = 0; fn < 2; ++fn) {
          acc[fm][fn] = __builtin_amdgcn_mfma_f32_16x16x32_bf16(aF[fm], bHF[fn], acc[fm][fn], 0, 0, 0);
          acc[fm][fn] = __builtin_amdgcn_mfma_f32_16x16x32_bf16(aF[fm], bLF[fn], acc[fm][fn], 0, 0, 0);
        }
    }
  }
  // ---- epilogue: C col = lane&15, row = (lane>>4)*4 + reg (m89/m91) ----
  int cn = lane & 15, rq = lane >> 4;
  #pragma unroll
  for (int fn = 0; fn < 2; ++fn) {
    int n = n0 + wn * 32 + fn * 16 + cn;
    float bias = b2[n];
    #pragma unroll
    for (int fm = 0; fm < 4; ++fm) {
      #pragma unroll
      for (int j = 0; j < 4; ++j) {
        int m = m0 + wm * 64 + fm * 16 + rq * 4 + j;
        qt[(size_t)m * 512 + n] = acc[fm][fn][j] + bias;
      }
    }
  }
}

// ---------------- scores + softmax: a[n][l] (unchanged from R2) ----------------
__global__ __launch_bounds__(256) void k_scores(
    const float* __restrict__ qt, const float* __restrict__ kk_,
    const float* __restrict__ msk, const int* __restrict__ starts,
    float* __restrict__ a_out) {
  int g = blockIdx.x >> 1;
  int half = blockIdx.x & 1;
  int t = threadIdx.x;
  int s0 = starts[g], s1 = starts[g + 1];
  if (s1 - s0 <= half * 16) return;

  __shared__ __align__(16) float qt_lds[16][DD];
  __shared__ __align__(16) float sred[4][16][LL];
  __shared__ __align__(16) float s_lds[LL][16];
  __shared__ float bias_lds[LL];

  if (t < LL) {
    float mv = msk[g * LL + t];
    bias_lds[t] = __expf(50.0f * (1.0f - mv)) - 1.0f;
  }

  for (int cs = s0 + half * 16; cs < s1; cs += 32) {
    int qc = min(16, s1 - cs);
    __syncthreads();
    #pragma unroll
    for (int r = 0; r < 8; ++r) {
      int idx = r * 256 + t;
      int q = idx >> 7, d4 = idx & 127;
      float4 val = make_float4(0.f, 0.f, 0.f, 0.f);
      if (q < qc) val = *(const float4*)&qt[(size_t)(cs + q) * DD + d4 * 4];
      *(float4*)&qt_lds[q][d4 * 4] = val;
    }
    __syncthreads();
    {
      int l2 = t & 31, dc = t >> 5;
      const float* kb0 = kk_ + ((size_t)g * LL + l2 * 2) * DD + dc * 64;
      const float* kb1 = kb0 + DD;
      float acc0[16], acc1[16];
      #pragma unroll
      for (int q = 0; q < 16; ++q) { acc0[q] = 0.f; acc1[q] = 0.f; }
      #pragma unroll
      for (int d4 = 0; d4 < 16; ++d4) {
        float4 kv0 = *(const float4*)&kb0[d4 * 4];
        float4 kv1 = *(const float4*)&kb1[d4 * 4];
        #pragma unroll
        for (int q = 0; q < 16; ++q) {
          float4 qv = *(const float4*)&qt_lds[q][dc * 64 + d4 * 4];
          acc0[q] += kv0.x*qv.x + kv0.y*qv.y + kv0.z*qv.z + kv0.w*qv.w;
          acc1[q] += kv1.x*qv.x + kv1.y*qv.y + kv1.z*qv.z + kv1.w*qv.w;
        }
      }
      #pragma unroll
      for (int q = 0; q < 16; ++q) {
        acc0[q] += __shfl_xor(acc0[q], 32);
        acc1[q] += __shfl_xor(acc1[q], 32);
      }
      if ((t & 32) == 0) {
        int w = t >> 6;
        #pragma unroll
        for (int q = 0; q < 16; ++q) {
          sred[w][q][l2 * 2]     = acc0[q];
          sred[w][q][l2 * 2 + 1] = acc1[q];
        }
      }
    }
    __syncthreads();
    #pragma unroll
    for (int r = 0; r < 4; ++r) {
      int idx = r * 256 + t;
      int q = idx >> 6, l = idx & 63;
      float ssum = 0.f;
      #pragma unroll
      for (int dc = 0; dc < 4; ++dc) ssum += sred[dc][q][l];
      s_lds[l][q] = ssum * 0.044194173824159216f - bias_lds[l];
    }
    __syncthreads();
    {
      int q = t >> 4, i = t & 15;
      float sv0 = s_lds[i][q], sv1 = s_lds[i + 16][q];
      float sv2 = s_lds[i + 32][q], sv3 = s_lds[i + 48][q];
      float mx = fmaxf(fmaxf(sv0, sv1), fmaxf(sv2, sv3));
      #pragma unroll
      for (int off = 1; off < 16; off <<= 1) mx = fmaxf(mx, __shfl_xor(mx, off, 16));
      float e0 = __expf(sv0 - mx), e1 = __expf(sv1 - mx);
      float e2 = __expf(sv2 - mx), e3 = __expf(sv3 - mx);
      float sum = e0 + e1 + e2 + e3;
      #pragma unroll
      for (int off = 1; off < 16; off <<= 1) sum += __shfl_xor(sum, off, 16);
      float inv = 1.0f / sum;
      if (q < qc) {
        float* ap = a_out + (size_t)(cs + q) * LL;
        ap[i]      = e0 * inv;
        ap[i + 16] = e1 * inv;
        ap[i + 32] = e2 * inv;
        ap[i + 48] = e3 * inv;
      }
    }
  }
}

// ---------------- PV: out[n][d] = sum_l a[n][l] * v[g][l][d] (unchanged) -------
__global__ __launch_bounds__(256) void k_pv(
    const float* __restrict__ a_in, const float* __restrict__ vv_,
    const int* __restrict__ starts, float* __restrict__ out) {
  int g = blockIdx.x >> 2;
  int half = (blockIdx.x >> 1) & 1;
  int dh = blockIdx.x & 1;
  int t = threadIdx.x;
  int s0 = starts[g], s1 = starts[g + 1];
  if (s1 - s0 <= half * 16) return;

  __shared__ __align__(16) float al[LL][17];

  int d4 = t & 63, qh = t >> 6;
  const float* vb = vv_ + (size_t)g * LL * DD + dh * 256 + d4 * 4;

  for (int cs = s0 + half * 16; cs < s1; cs += 32) {
    int qc = min(16, s1 - cs);
    __syncthreads();
    {
      int q = t >> 4, l4 = t & 15;
      int row = min(cs + q, NQ - 1);
      float4 av = *(const float4*)&a_in[(size_t)row * LL + l4 * 4];
      al[l4 * 4 + 0][q] = av.x; al[l4 * 4 + 1][q] = av.y;
      al[l4 * 4 + 2][q] = av.z; al[l4 * 4 + 3][q] = av.w;
    }
    __syncthreads();
    float o[4][4];
    #pragma unroll
    for (int u = 0; u < 4; ++u) { o[u][0]=0.f; o[u][1]=0.f; o[u][2]=0.f; o[u][3]=0.f; }
    #pragma unroll 8
    for (int l = 0; l < LL; ++l) {
      float4 vv = *(const float4*)&vb[(size_t)l * DD];
      float4 aa = *(const float4*)&al[l][qh * 4];
      float av[4] = {aa.x, aa.y, aa.z, aa.w};
      #pragma unroll
      for (int u = 0; u < 4; ++u) {
        o[u][0] += av[u] * vv.x; o[u][1] += av[u] * vv.y;
        o[u][2] += av[u] * vv.z; o[u][3] += av[u] * vv.w;
      }
    }
    #pragma unroll
    for (int u = 0; u < 4; ++u) {
      int q = qh * 4 + u;
      if (q < qc) {
        float4 ov = make_float4(o[u][0], o[u][1], o[u][2], o[u][3]);
        *(float4*)&out[(size_t)(cs + q) * DD + dh * 256 + d4 * 4] = ov;
      }
    }
  }
}

extern "C" void kernel_launch(void* const* d_in, const int* in_sizes, int n_in,
                              void* d_out, int out_size, void* d_ws, size_t ws_size,
                              hipStream_t stream) {
  const float* q_in = (const float*)d_in[0];
  const float* k_in = (const float*)d_in[1];
  const float* v_in = (const float*)d_in[2];
  const float* m_in = (const float*)d_in[3];
  const int*   gid  = (const int*)d_in[4];
  const float* Wq   = (const float*)d_in[5];
  const float* bq   = (const float*)d_in[6];
  const float* Wk   = (const float*)d_in[7];
  // d_in[8] = bk: per-query constant on all scores -> cancels in softmax.
  float* out = (float*)d_out;

  // ws carve: w2t_h[512*1024]us | w2t_l[512*1024]us | b2[512]f | starts[512]i | qt[4096*512]f
  // a[4096*64]f aliases w2t_h (dead after gemm_qt_mfma). Total ~10.25 MB.
  unsigned short* w2t_h = (unsigned short*)d_ws;
  unsigned short* w2t_l = w2t_h + 512 * 1024;
  float* b2 = (float*)(w2t_l + 512 * 1024);
  int* starts = (int*)(b2 + 512);
  float* qt = (float*)(starts + 512);
  float* a = (float*)d_ws;  // alias w2t_h region (exactly 1 MB)

  k_starts<<<2, 256, 0, stream>>>(gid, starts);
  k_b2<<<2, 256, 0, stream>>>(Wk, bq, b2);
  // W2T = Wk @ Wq^T, split bf16 hi/lo: grid (N=1024/64, M=512/32)
  gemm_w2t<<<dim3(16, 16), 256, 0, stream>>>(Wk, Wq, w2t_h, w2t_l);
  // qt = q @ W2 + b2 via MFMA: grid (512/64, 4096/128)
  gemm_qt_mfma<<<dim3(8, 32), 256, 0, stream>>>(q_in, w2t_h, w2t_l, b2, qt);
  // scores + softmax -> a
  k_scores<<<512, 256, 0, stream>>>(qt, k_in, m_in, starts, a);
  // out = a @ v (grouped)
  k_pv<<<1024, 256, 0, stream>>>(a, v_in, starts, out);
}

// Round 4
// 128.292 us; speedup vs baseline: 1.8794x; 1.1994x over previous
//
#include <hip/hip_runtime.h>

#define NQ   4096
#define NGRP 256
#define LL   64
#define DD   512

typedef __attribute__((ext_vector_type(8))) short short8v;
typedef __attribute__((ext_vector_type(4))) float f32x4;
typedef __attribute__((ext_vector_type(4))) unsigned short us4v;

// float -> bf16 bits, round-to-nearest-even
static __device__ __forceinline__ unsigned short f2bf(float f) {
  union { float f; unsigned u; } x{f};
  unsigned r = x.u + 0x7fffu + ((x.u >> 16) & 1u);
  return (unsigned short)(r >> 16);
}
static __device__ __forceinline__ float bf2f(unsigned short h) {
  union { unsigned u; float f; } x{(unsigned)h << 16};
  return x.f;
}

// split fp32 float4 -> hi/lo bf16 into XOR-slot-swizzled LDS tile [rows][8 slots of us8]
static __device__ __forceinline__ void split_store(
    unsigned short* Hh, unsigned short* Hl, int r, int c4, float4 v) {
  int s = c4 >> 1, hf = c4 & 1;
  int base = (r * 8 + (s ^ (r & 7))) * 8 + hf * 4;
  unsigned short h0 = f2bf(v.x), h1 = f2bf(v.y), h2 = f2bf(v.z), h3 = f2bf(v.w);
  us4v hv = {h0, h1, h2, h3};
  us4v lv = {f2bf(v.x - bf2f(h0)), f2bf(v.y - bf2f(h1)),
             f2bf(v.z - bf2f(h2)), f2bf(v.w - bf2f(h3))};
  *(us4v*)(Hh + base) = hv;
  *(us4v*)(Hl + base) = lv;
}

// MFMA fragment load from swizzled LDS tile
static __device__ __forceinline__ short8v frag(const unsigned short* P, int r, int sl) {
  return *(const short8v*)(P + (r * 8 + (sl ^ (r & 7))) * 8);
}

// ---------------- group starts: starts[g] = lower_bound(gid, g) ----------------
__global__ __launch_bounds__(256) void k_starts(const int* __restrict__ gid,
                                                int* __restrict__ starts) {
  int g = blockIdx.x * 256 + threadIdx.x;
  if (g > NGRP) return;
  int lo = 0, hi = NQ;
  while (lo < hi) { int mid = (lo + hi) >> 1; if (gid[mid] < g) lo = mid + 1; else hi = mid; }
  starts[g] = lo;
}

// ---------------- b2[d] = sum_j Wk[d][j] * bq[j] ----------------
__global__ __launch_bounds__(256) void k_b2(const float* __restrict__ Wk,
                                            const float* __restrict__ bq,
                                            float* __restrict__ b2) {
  int dd = blockIdx.x * 256 + threadIdx.x;
  if (dd >= DD) return;
  float s = 0.f;
  const float* row = Wk + (size_t)dd * DD;
  for (int j = 0; j < DD; j += 4) {
    float4 w = *(const float4*)&row[j];
    float4 b = *(const float4*)&bq[j];
    s += w.x*b.x + w.y*b.y + w.z*b.z + w.w*b.w;
  }
  b2[dd] = s;
}

// ---------------- W2T = Wk @ Wq^T via 3-term split-bf16 MFMA ----------------
// C[m=512][n=1024] = sum_k Wk[m][k]*Wq[n][k]. Both operands split in-flight.
// BM=BN=BK=64, grid (16 n, 8 m), 4 waves (2x2). Output split bf16 hi/lo.
__global__ __launch_bounds__(256) void gemm_w2t_mfma(
    const float* __restrict__ Wk, const float* __restrict__ Wq,
    unsigned short* __restrict__ w2t_h, unsigned short* __restrict__ w2t_l) {
  __shared__ __align__(16) unsigned short Ah[64*64], Al[64*64];  // 8 KB each
  __shared__ __align__(16) unsigned short Bh[64*64], Bl[64*64];
  int t = threadIdx.x, lane = t & 63, wid = t >> 6;
  int wm = wid >> 1, wn = wid & 1;
  int n0 = blockIdx.x * 64, m0 = blockIdx.y * 64;
  f32x4 acc[2][2];
  #pragma unroll
  for (int i = 0; i < 2; ++i)
    #pragma unroll
    for (int j = 0; j < 2; ++j) acc[i][j] = (f32x4){0.f,0.f,0.f,0.f};

  for (int k0 = 0; k0 < 512; k0 += 64) {
    __syncthreads();
    #pragma unroll
    for (int i = 0; i < 4; ++i) {
      int idx = i * 256 + t, r = idx >> 4, c4 = idx & 15;
      float4 vA = *(const float4*)&Wk[(size_t)(m0 + r) * 512 + k0 + c4 * 4];
      split_store(Ah, Al, r, c4, vA);
      float4 vB = *(const float4*)&Wq[(size_t)(n0 + r) * 512 + k0 + c4 * 4];
      split_store(Bh, Bl, r, c4, vB);
    }
    __syncthreads();
    #pragma unroll
    for (int kk = 0; kk < 2; ++kk) {
      int sl = kk * 4 + (lane >> 4);
      short8v aH[2], aL[2], bH[2], bL[2];
      #pragma unroll
      for (int fm = 0; fm < 2; ++fm) {
        int r = wm * 32 + fm * 16 + (lane & 15);
        aH[fm] = frag(Ah, r, sl); aL[fm] = frag(Al, r, sl);
      }
      #pragma unroll
      for (int fn = 0; fn < 2; ++fn) {
        int r = wn * 32 + fn * 16 + (lane & 15);
        bH[fn] = frag(Bh, r, sl); bL[fn] = frag(Bl, r, sl);
      }
      #pragma unroll
      for (int fm = 0; fm < 2; ++fm)
        #pragma unroll
        for (int fn = 0; fn < 2; ++fn) {
          acc[fm][fn] = __builtin_amdgcn_mfma_f32_16x16x32_bf16(aH[fm], bH[fn], acc[fm][fn], 0, 0, 0);
          acc[fm][fn] = __builtin_amdgcn_mfma_f32_16x16x32_bf16(aH[fm], bL[fn], acc[fm][fn], 0, 0, 0);
          acc[fm][fn] = __builtin_amdgcn_mfma_f32_16x16x32_bf16(aL[fm], bH[fn], acc[fm][fn], 0, 0, 0);
        }
    }
  }
  int cn = lane & 15, rq = lane >> 4;
  #pragma unroll
  for (int fm = 0; fm < 2; ++fm)
    #pragma unroll
    for (int fn = 0; fn < 2; ++fn)
      #pragma unroll
      for (int j = 0; j < 4; ++j) {
        int m = m0 + wm * 32 + fm * 16 + rq * 4 + j;
        int n = n0 + wn * 32 + fn * 16 + cn;
        float c = acc[fm][fn][j];
        unsigned short hi = f2bf(c);
        unsigned short lo = f2bf(c - bf2f(hi));
        size_t off = (size_t)m * 1024 + n;
        w2t_h[off] = hi; w2t_l[off] = lo;
      }
}

// ---------------- qt = q @ W2 + b2 via split-bf16 MFMA; emits qt split hi/lo ----
// M=4096, N=512, K=1024. A = bf16(q) in-flight; B = W2T hi/lo [512][1024].
__global__ __launch_bounds__(256) void gemm_qt_mfma(
    const float* __restrict__ q_in,
    const unsigned short* __restrict__ w2t_h,
    const unsigned short* __restrict__ w2t_l,
    const float* __restrict__ b2,
    unsigned short* __restrict__ qt_h, unsigned short* __restrict__ qt_l) {
  __shared__ __align__(16) unsigned short As[128 * 64];  // 16 KB
  __shared__ __align__(16) unsigned short Bh[64 * 64];   // 8 KB
  __shared__ __align__(16) unsigned short Bl[64 * 64];   // 8 KB
  int t = threadIdx.x;
  int lane = t & 63, wid = t >> 6;
  int wm = wid >> 1, wn = wid & 1;
  int n0 = blockIdx.x * 64, m0 = blockIdx.y * 128;

  f32x4 acc[4][2];
  #pragma unroll
  for (int i = 0; i < 4; ++i)
    #pragma unroll
    for (int j = 0; j < 2; ++j) acc[i][j] = (f32x4){0.f, 0.f, 0.f, 0.f};

  for (int k0 = 0; k0 < 1024; k0 += 64) {
    __syncthreads();
    #pragma unroll
    for (int i = 0; i < 4; ++i) {
      int idx = i * 256 + t;
      int r = idx >> 3, s = idx & 7;
      const float* src = q_in + (size_t)(m0 + r) * 1024 + k0 + s * 8;
      float4 f0 = *(const float4*)src;
      float4 f1 = *(const float4*)(src + 4);
      uint4 pk;
      pk.x = (unsigned)f2bf(f0.x) | ((unsigned)f2bf(f0.y) << 16);
      pk.y = (unsigned)f2bf(f0.z) | ((unsigned)f2bf(f0.w) << 16);
      pk.z = (unsigned)f2bf(f1.x) | ((unsigned)f2bf(f1.y) << 16);
      pk.w = (unsigned)f2bf(f1.z) | ((unsigned)f2bf(f1.w) << 16);
      ((uint4*)As)[r * 8 + (s ^ (r & 7))] = pk;
    }
    #pragma unroll
    for (int i = 0; i < 2; ++i) {
      int idx = i * 256 + t;
      int r = idx >> 3, s = idx & 7;
      int dst = r * 8 + (s ^ (r & 7));
      ((uint4*)Bh)[dst] = *(const uint4*)(w2t_h + (size_t)(n0 + r) * 1024 + k0 + s * 8);
      ((uint4*)Bl)[dst] = *(const uint4*)(w2t_l + (size_t)(n0 + r) * 1024 + k0 + s * 8);
    }
    __syncthreads();
    #pragma unroll
    for (int kk = 0; kk < 2; ++kk) {
      short8v aF[4], bHF[2], bLF[2];
      int sl = kk * 4 + (lane >> 4);
      #pragma unroll
      for (int fm = 0; fm < 4; ++fm)
        aF[fm] = frag(As, wm * 64 + fm * 16 + (lane & 15), sl);
      #pragma unroll
      for (int fn = 0; fn < 2; ++fn) {
        int r = wn * 32 + fn * 16 + (lane & 15);
        bHF[fn] = frag(Bh, r, sl);
        bLF[fn] = frag(Bl, r, sl);
      }
      #pragma unroll
      for (int fm = 0; fm < 4; ++fm)
        #pragma unroll
        for (int fn = 0; fn < 2; ++fn) {
          acc[fm][fn] = __builtin_amdgcn_mfma_f32_16x16x32_bf16(aF[fm], bHF[fn], acc[fm][fn], 0, 0, 0);
          acc[fm][fn] = __builtin_amdgcn_mfma_f32_16x16x32_bf16(aF[fm], bLF[fn], acc[fm][fn], 0, 0, 0);
        }
    }
  }
  int cn = lane & 15, rq = lane >> 4;
  #pragma unroll
  for (int fn = 0; fn < 2; ++fn) {
    int n = n0 + wn * 32 + fn * 16 + cn;
    float bias = b2[n];
    #pragma unroll
    for (int fm = 0; fm < 4; ++fm)
      #pragma unroll
      for (int j = 0; j < 4; ++j) {
        int m = m0 + wm * 64 + fm * 16 + rq * 4 + j;
        float val = acc[fm][fn][j] + bias;
        unsigned short hi = f2bf(val);
        unsigned short lo = f2bf(val - bf2f(hi));
        qt_h[(size_t)m * 512 + n] = hi;
        qt_l[(size_t)m * 512 + n] = lo;
      }
  }
}

// ---------------- scores + softmax via MFMA: a[n][l] ----------------
// One block per group, 4 waves. S[64 l][32 q] = K @ qt^T, 3-term split bf16.
// Wave w owns l-tile w; K streamed in 64x64 d-tiles (fp32 -> split in-flight).
__global__ __launch_bounds__(256) void k_scores_mfma(
    const unsigned short* __restrict__ qt_h, const unsigned short* __restrict__ qt_l,
    const float* __restrict__ kk_, const float* __restrict__ msk,
    const int* __restrict__ starts, float* __restrict__ a_out) {
  int g = blockIdx.x;
  int t = threadIdx.x, lane = t & 63, wid = t >> 6;
  int s0 = starts[g], s1 = starts[g + 1];
  if (s0 >= s1) return;

  __shared__ __align__(16) unsigned short Kh[64*64], Kl[64*64];  // 8 KB each
  __shared__ __align__(16) unsigned short Qh[32*64], Ql[32*64];  // 4 KB each
  __shared__ float S_lds[LL][33];                                 // 8.25 KB
  __shared__ float bias_lds[LL];

  if (t < LL) bias_lds[t] = __expf(50.0f * (1.0f - msk[g * LL + t])) - 1.0f;

  for (int cs = s0; cs < s1; cs += 32) {
    int qc = min(32, s1 - cs);
    f32x4 acc[2];
    acc[0] = (f32x4){0.f,0.f,0.f,0.f};
    acc[1] = (f32x4){0.f,0.f,0.f,0.f};

    for (int k0 = 0; k0 < DD; k0 += 64) {
      __syncthreads();
      // stage K 64x64 fp32 tile -> split hi/lo
      #pragma unroll
      for (int i = 0; i < 4; ++i) {
        int idx = i * 256 + t, r = idx >> 4, c4 = idx & 15;
        float4 v = *(const float4*)&kk_[((size_t)g * LL + r) * DD + k0 + c4 * 4];
        split_store(Kh, Kl, r, c4, v);
      }
      // stage qt tiles (pre-split in global)
      {
        int r = t >> 3, s = t & 7;
        uint4 vh = make_uint4(0,0,0,0), vl = make_uint4(0,0,0,0);
        if (r < qc) {
          vh = *(const uint4*)&qt_h[(size_t)(cs + r) * DD + k0 + s * 8];
          vl = *(const uint4*)&qt_l[(size_t)(cs + r) * DD + k0 + s * 8];
        }
        int slot = r * 8 + (s ^ (r & 7));
        ((uint4*)Qh)[slot] = vh;
        ((uint4*)Ql)[slot] = vl;
      }
      __syncthreads();
      #pragma unroll
      for (int kk = 0; kk < 2; ++kk) {
        int sl = kk * 4 + (lane >> 4);
        int rA = wid * 16 + (lane & 15);
        short8v aH = frag(Kh, rA, sl), aL = frag(Kl, rA, sl);
        #pragma unroll
        for (int fn = 0; fn < 2; ++fn) {
          int rB = fn * 16 + (lane & 15);
          short8v bH = frag(Qh, rB, sl), bL = frag(Ql, rB, sl);
          acc[fn] = __builtin_amdgcn_mfma_f32_16x16x32_bf16(aH, bH, acc[fn], 0, 0, 0);
          acc[fn] = __builtin_amdgcn_mfma_f32_16x16x32_bf16(aH, bL, acc[fn], 0, 0, 0);
          acc[fn] = __builtin_amdgcn_mfma_f32_16x16x32_bf16(aL, bH, acc[fn], 0, 0, 0);
        }
      }
    }
    // write S (scaled, mask-biased): C row = l-in-tile, col = q
    {
      int cq = lane & 15, rq = lane >> 4;
      #pragma unroll
      for (int fn = 0; fn < 2; ++fn)
        #pragma unroll
        for (int j = 0; j < 4; ++j) {
          int l = wid * 16 + rq * 4 + j;
          S_lds[l][fn * 16 + cq] = acc[fn][j] * 0.044194173824159216f - bias_lds[l];
        }
    }
    __syncthreads();
    // softmax over l: 8 lanes per query (q = t>>3, i = t&7)
    {
      int q = t >> 3, i = t & 7;
      float sv[8];
      #pragma unroll
      for (int j = 0; j < 8; ++j) sv[j] = S_lds[i + 8 * j][q];
      float mx = sv[0];
      #pragma unroll
      for (int j = 1; j < 8; ++j) mx = fmaxf(mx, sv[j]);
      #pragma unroll
      for (int off = 1; off < 8; off <<= 1) mx = fmaxf(mx, __shfl_xor(mx, off, 8));
      float e[8], sum = 0.f;
      #pragma unroll
      for (int j = 0; j < 8; ++j) { e[j] = __expf(sv[j] - mx); sum += e[j]; }
      #pragma unroll
      for (int off = 1; off < 8; off <<= 1) sum += __shfl_xor(sum, off, 8);
      float inv = 1.0f / sum;
      if (q < qc) {
        float* ap = a_out + (size_t)(cs + q) * LL;
        #pragma unroll
        for (int j = 0; j < 8; ++j) ap[i + 8 * j] = e[j] * inv;
      }
    }
    __syncthreads();
  }
}

// ---------------- PV: out[n][d] = sum_l a[n][l] * v[g][l][d] ----------------
// Grid: 256 groups x 4 d-quarters = 1024 blocks. Thread: d4 = t&31 (4 d),
// qh = t>>5 (2 queries). Tiny LDS (4.4 KB) -> high occupancy.
__global__ __launch_bounds__(256) void k_pv(
    const float* __restrict__ a_in, const float* __restrict__ vv_,
    const int* __restrict__ starts, float* __restrict__ out) {
  int g = blockIdx.x >> 2, dq = blockIdx.x & 3;
  int t = threadIdx.x;
  int s0 = starts[g], s1 = starts[g + 1];
  if (s0 >= s1) return;

  __shared__ __align__(16) float al[LL][17];

  int d4 = t & 31, qh = t >> 5;
  const float* vb = vv_ + (size_t)g * LL * DD + dq * 128 + d4 * 4;

  for (int cs = s0; cs < s1; cs += 16) {
    int qc = min(16, s1 - cs);
    __syncthreads();
    {
      int q = t >> 4, l4 = t & 15;
      int row = min(cs + q, NQ - 1);
      float4 av = *(const float4*)&a_in[(size_t)row * LL + l4 * 4];
      al[l4 * 4 + 0][q] = av.x; al[l4 * 4 + 1][q] = av.y;
      al[l4 * 4 + 2][q] = av.z; al[l4 * 4 + 3][q] = av.w;
    }
    __syncthreads();
    float o0[4] = {0.f,0.f,0.f,0.f}, o1[4] = {0.f,0.f,0.f,0.f};
    #pragma unroll 8
    for (int l = 0; l < LL; ++l) {
      float4 vv = *(const float4*)&vb[(size_t)l * DD];
      float a0 = al[l][qh * 2], a1 = al[l][qh * 2 + 1];
      o0[0] += a0 * vv.x; o0[1] += a0 * vv.y; o0[2] += a0 * vv.z; o0[3] += a0 * vv.w;
      o1[0] += a1 * vv.x; o1[1] += a1 * vv.y; o1[2] += a1 * vv.z; o1[3] += a1 * vv.w;
    }
    int q0 = qh * 2, q1 = qh * 2 + 1;
    if (q0 < qc)
      *(float4*)&out[(size_t)(cs + q0) * DD + dq * 128 + d4 * 4] =
          make_float4(o0[0], o0[1], o0[2], o0[3]);
    if (q1 < qc)
      *(float4*)&out[(size_t)(cs + q1) * DD + dq * 128 + d4 * 4] =
          make_float4(o1[0], o1[1], o1[2], o1[3]);
  }
}

extern "C" void kernel_launch(void* const* d_in, const int* in_sizes, int n_in,
                              void* d_out, int out_size, void* d_ws, size_t ws_size,
                              hipStream_t stream) {
  const float* q_in = (const float*)d_in[0];
  const float* k_in = (const float*)d_in[1];
  const float* v_in = (const float*)d_in[2];
  const float* m_in = (const float*)d_in[3];
  const int*   gid  = (const int*)d_in[4];
  const float* Wq   = (const float*)d_in[5];
  const float* bq   = (const float*)d_in[6];
  const float* Wk   = (const float*)d_in[7];
  // d_in[8] = bk: per-query constant on all scores -> cancels in softmax.
  float* out = (float*)d_out;

  // ws carve: w2t_h[512*1024]us | w2t_l[512*1024]us | qt_h[4096*512]us |
  //           qt_l[4096*512]us | b2[512]f | starts[512]i   (~10 MB)
  // a[4096*64]f aliases w2t_h (dead after gemm_qt_mfma).
  unsigned short* w2t_h = (unsigned short*)d_ws;
  unsigned short* w2t_l = w2t_h + 512 * 1024;
  unsigned short* qt_h  = w2t_l + 512 * 1024;
  unsigned short* qt_l  = qt_h + 4096 * 512;
  float* b2 = (float*)(qt_l + 4096 * 512);
  int* starts = (int*)(b2 + 512);
  float* a = (float*)d_ws;  // alias w2t_h region (exactly 1 MB)

  k_starts<<<2, 256, 0, stream>>>(gid, starts);
  k_b2<<<2, 256, 0, stream>>>(Wk, bq, b2);
  // W2T = Wk @ Wq^T, split bf16 hi/lo: grid (1024/64, 512/64)
  gemm_w2t_mfma<<<dim3(16, 8), 256, 0, stream>>>(Wk, Wq, w2t_h, w2t_l);
  // qt = q @ W2 + b2, emitted as split bf16: grid (512/64, 4096/128)
  gemm_qt_mfma<<<dim3(8, 32), 256, 0, stream>>>(q_in, w2t_h, w2t_l, b2, qt_h, qt_l);
  // scores + softmax -> a (one block per group)
  k_scores_mfma<<<NGRP, 256, 0, stream>>>(qt_h, qt_l, k_in, m_in, starts, a);
  // out = a @ v (grouped, 4-way d split)
  k_pv<<<NGRP * 4, 256, 0, stream>>>(a, v_in, starts, out);
}

// Round 5
// 112.754 us; speedup vs baseline: 2.1384x; 1.1378x over previous
//
#include <hip/hip_runtime.h>

#define NQ   4096
#define NGRP 256
#define LL   64
#define DD   512

typedef __attribute__((ext_vector_type(8))) short short8v;
typedef __attribute__((ext_vector_type(4))) float f32x4;
typedef __attribute__((ext_vector_type(4))) unsigned short us4v;

// float -> bf16 bits, round-to-nearest-even
static __device__ __forceinline__ unsigned short f2bf(float f) {
  union { float f; unsigned u; } x{f};
  unsigned r = x.u + 0x7fffu + ((x.u >> 16) & 1u);
  return (unsigned short)(r >> 16);
}
static __device__ __forceinline__ float bf2f(unsigned short h) {
  union { unsigned u; float f; } x{(unsigned)h << 16};
  return x.f;
}

// split fp32 float4 -> hi/lo bf16 into XOR-slot-swizzled LDS tile [rows][8 slots of us8]
static __device__ __forceinline__ void split_store(
    unsigned short* Hh, unsigned short* Hl, int r, int c4, float4 v) {
  int s = c4 >> 1, hf = c4 & 1;
  int base = (r * 8 + (s ^ (r & 7))) * 8 + hf * 4;
  unsigned short h0 = f2bf(v.x), h1 = f2bf(v.y), h2 = f2bf(v.z), h3 = f2bf(v.w);
  us4v hv = {h0, h1, h2, h3};
  us4v lv = {f2bf(v.x - bf2f(h0)), f2bf(v.y - bf2f(h1)),
             f2bf(v.z - bf2f(h2)), f2bf(v.w - bf2f(h3))};
  *(us4v*)(Hh + base) = hv;
  *(us4v*)(Hl + base) = lv;
}

// MFMA fragment load from swizzled LDS tile
static __device__ __forceinline__ short8v frag(const unsigned short* P, int r, int sl) {
  return *(const short8v*)(P + (r * 8 + (sl ^ (r & 7))) * 8);
}

// ---------------- group starts ----------------
__global__ __launch_bounds__(256) void k_starts(const int* __restrict__ gid,
                                                int* __restrict__ starts) {
  int g = blockIdx.x * 256 + threadIdx.x;
  if (g > NGRP) return;
  int lo = 0, hi = NQ;
  while (lo < hi) { int mid = (lo + hi) >> 1; if (gid[mid] < g) lo = mid + 1; else hi = mid; }
  starts[g] = lo;
}

// ---------------- b2[d] = sum_j Wk[d][j] * bq[j] ----------------
__global__ __launch_bounds__(256) void k_b2(const float* __restrict__ Wk,
                                            const float* __restrict__ bq,
                                            float* __restrict__ b2) {
  int dd = blockIdx.x * 256 + threadIdx.x;
  if (dd >= DD) return;
  float s = 0.f;
  const float* row = Wk + (size_t)dd * DD;
  for (int j = 0; j < DD; j += 4) {
    float4 w = *(const float4*)&row[j];
    float4 b = *(const float4*)&bq[j];
    s += w.x*b.x + w.y*b.y + w.z*b.z + w.w*b.w;
  }
  b2[dd] = s;
}

// ---------------- q fp32 -> bf16 (streaming) ----------------
__global__ __launch_bounds__(256) void k_qbf(const float* __restrict__ q_in,
                                             unsigned short* __restrict__ qbf) {
  int idx = blockIdx.x * 256 + threadIdx.x;     // one uint4 (8 bf16) per thread
  const float* src = q_in + (size_t)idx * 8;
  float4 f0 = *(const float4*)src;
  float4 f1 = *(const float4*)(src + 4);
  uint4 pk;
  pk.x = (unsigned)f2bf(f0.x) | ((unsigned)f2bf(f0.y) << 16);
  pk.y = (unsigned)f2bf(f0.z) | ((unsigned)f2bf(f0.w) << 16);
  pk.z = (unsigned)f2bf(f1.x) | ((unsigned)f2bf(f1.y) << 16);
  pk.w = (unsigned)f2bf(f1.z) | ((unsigned)f2bf(f1.w) << 16);
  ((uint4*)qbf)[idx] = pk;
}

// ---------------- W2T = Wk @ Wq^T via 3-term split-bf16 MFMA ----------------
__global__ __launch_bounds__(256) void gemm_w2t_mfma(
    const float* __restrict__ Wk, const float* __restrict__ Wq,
    unsigned short* __restrict__ w2t_h, unsigned short* __restrict__ w2t_l) {
  __shared__ __align__(16) unsigned short Ah[64*64], Al[64*64];
  __shared__ __align__(16) unsigned short Bh[64*64], Bl[64*64];
  int t = threadIdx.x, lane = t & 63, wid = t >> 6;
  int wm = wid >> 1, wn = wid & 1;
  int n0 = blockIdx.x * 64, m0 = blockIdx.y * 64;
  f32x4 acc[2][2];
  #pragma unroll
  for (int i = 0; i < 2; ++i)
    #pragma unroll
    for (int j = 0; j < 2; ++j) acc[i][j] = (f32x4){0.f,0.f,0.f,0.f};

  for (int k0 = 0; k0 < 512; k0 += 64) {
    __syncthreads();
    #pragma unroll
    for (int i = 0; i < 4; ++i) {
      int idx = i * 256 + t, r = idx >> 4, c4 = idx & 15;
      float4 vA = *(const float4*)&Wk[(size_t)(m0 + r) * 512 + k0 + c4 * 4];
      split_store(Ah, Al, r, c4, vA);
      float4 vB = *(const float4*)&Wq[(size_t)(n0 + r) * 512 + k0 + c4 * 4];
      split_store(Bh, Bl, r, c4, vB);
    }
    __syncthreads();
    #pragma unroll
    for (int kk = 0; kk < 2; ++kk) {
      int sl = kk * 4 + (lane >> 4);
      short8v aH[2], aL[2], bH[2], bL[2];
      #pragma unroll
      for (int fm = 0; fm < 2; ++fm) {
        int r = wm * 32 + fm * 16 + (lane & 15);
        aH[fm] = frag(Ah, r, sl); aL[fm] = frag(Al, r, sl);
      }
      #pragma unroll
      for (int fn = 0; fn < 2; ++fn) {
        int r = wn * 32 + fn * 16 + (lane & 15);
        bH[fn] = frag(Bh, r, sl); bL[fn] = frag(Bl, r, sl);
      }
      #pragma unroll
      for (int fm = 0; fm < 2; ++fm)
        #pragma unroll
        for (int fn = 0; fn < 2; ++fn) {
          acc[fm][fn] = __builtin_amdgcn_mfma_f32_16x16x32_bf16(aH[fm], bH[fn], acc[fm][fn], 0, 0, 0);
          acc[fm][fn] = __builtin_amdgcn_mfma_f32_16x16x32_bf16(aH[fm], bL[fn], acc[fm][fn], 0, 0, 0);
          acc[fm][fn] = __builtin_amdgcn_mfma_f32_16x16x32_bf16(aL[fm], bH[fn], acc[fm][fn], 0, 0, 0);
        }
    }
  }
  int cn = lane & 15, rq = lane >> 4;
  #pragma unroll
  for (int fm = 0; fm < 2; ++fm)
    #pragma unroll
    for (int fn = 0; fn < 2; ++fn)
      #pragma unroll
      for (int j = 0; j < 4; ++j) {
        int m = m0 + wm * 32 + fm * 16 + rq * 4 + j;
        int n = n0 + wn * 32 + fn * 16 + cn;
        float c = acc[fm][fn][j];
        unsigned short hi = f2bf(c);
        unsigned short lo = f2bf(c - bf2f(hi));
        size_t off = (size_t)m * 1024 + n;
        w2t_h[off] = hi; w2t_l[off] = lo;
      }
}

// ---------------- qt = q @ W2 + b2 via split-bf16 MFMA ----------------
// BM=BN=BK=64 -> grid (8, 64) = 512 blocks = 2 blocks/CU, 8 waves/CU.
// A read directly as bf16 (qbf). Emits qt split hi/lo.
__global__ __launch_bounds__(256) void gemm_qt_mfma(
    const unsigned short* __restrict__ qbf,       // [4096][1024] bf16
    const unsigned short* __restrict__ w2t_h,
    const unsigned short* __restrict__ w2t_l,
    const float* __restrict__ b2,
    unsigned short* __restrict__ qt_h, unsigned short* __restrict__ qt_l) {
  __shared__ __align__(16) unsigned short As[64 * 64];   // 8 KB
  __shared__ __align__(16) unsigned short Bh[64 * 64];   // 8 KB
  __shared__ __align__(16) unsigned short Bl[64 * 64];   // 8 KB
  int t = threadIdx.x;
  int lane = t & 63, wid = t >> 6;
  int wm = wid >> 1, wn = wid & 1;
  int n0 = blockIdx.x * 64, m0 = blockIdx.y * 64;

  f32x4 acc[2][2];
  #pragma unroll
  for (int i = 0; i < 2; ++i)
    #pragma unroll
    for (int j = 0; j < 2; ++j) acc[i][j] = (f32x4){0.f, 0.f, 0.f, 0.f};

  for (int k0 = 0; k0 < 1024; k0 += 64) {
    __syncthreads();
    #pragma unroll
    for (int i = 0; i < 2; ++i) {
      int idx = i * 256 + t;
      int r = idx >> 3, s = idx & 7;
      int dst = r * 8 + (s ^ (r & 7));
      ((uint4*)As)[dst] = *(const uint4*)(qbf + (size_t)(m0 + r) * 1024 + k0 + s * 8);
    }
    #pragma unroll
    for (int i = 0; i < 2; ++i) {
      int idx = i * 256 + t;
      int r = idx >> 3, s = idx & 7;
      int dst = r * 8 + (s ^ (r & 7));
      ((uint4*)Bh)[dst] = *(const uint4*)(w2t_h + (size_t)(n0 + r) * 1024 + k0 + s * 8);
      ((uint4*)Bl)[dst] = *(const uint4*)(w2t_l + (size_t)(n0 + r) * 1024 + k0 + s * 8);
    }
    __syncthreads();
    #pragma unroll
    for (int kk = 0; kk < 2; ++kk) {
      short8v aF[2], bHF[2], bLF[2];
      int sl = kk * 4 + (lane >> 4);
      #pragma unroll
      for (int fm = 0; fm < 2; ++fm)
        aF[fm] = frag(As, wm * 32 + fm * 16 + (lane & 15), sl);
      #pragma unroll
      for (int fn = 0; fn < 2; ++fn) {
        int r = wn * 32 + fn * 16 + (lane & 15);
        bHF[fn] = frag(Bh, r, sl);
        bLF[fn] = frag(Bl, r, sl);
      }
      #pragma unroll
      for (int fm = 0; fm < 2; ++fm)
        #pragma unroll
        for (int fn = 0; fn < 2; ++fn) {
          acc[fm][fn] = __builtin_amdgcn_mfma_f32_16x16x32_bf16(aF[fm], bHF[fn], acc[fm][fn], 0, 0, 0);
          acc[fm][fn] = __builtin_amdgcn_mfma_f32_16x16x32_bf16(aF[fm], bLF[fn], acc[fm][fn], 0, 0, 0);
        }
    }
  }
  int cn = lane & 15, rq = lane >> 4;
  #pragma unroll
  for (int fn = 0; fn < 2; ++fn) {
    int n = n0 + wn * 32 + fn * 16 + cn;
    float bias = b2[n];
    #pragma unroll
    for (int fm = 0; fm < 2; ++fm)
      #pragma unroll
      for (int j = 0; j < 4; ++j) {
        int m = m0 + wm * 32 + fm * 16 + rq * 4 + j;
        float val = acc[fm][fn][j] + bias;
        unsigned short hi = f2bf(val);
        unsigned short lo = f2bf(val - bf2f(hi));
        qt_h[(size_t)m * 512 + n] = hi;
        qt_l[(size_t)m * 512 + n] = lo;
      }
  }
}

// ---------------- scores + softmax via MFMA, 2-way split-D ----------------
// One block per group, 512 threads = 8 waves. Waves 0-3: d in [0,256);
// waves 4-7: d in [256,512). Wave wl owns l-tile wl. Partial-S combine in LDS.
__global__ __launch_bounds__(512) void k_scores_mfma(
    const unsigned short* __restrict__ qt_h, const unsigned short* __restrict__ qt_l,
    const float* __restrict__ kk_, const float* __restrict__ msk,
    const int* __restrict__ starts, float* __restrict__ a_out) {
  int g = blockIdx.x;
  int t = threadIdx.x, lane = t & 63, wid = t >> 6;
  int h = wid >> 2;        // d-half
  int wl = wid & 3;        // l-tile
  int th = t & 255;        // thread-in-half
  int s0 = starts[g], s1 = starts[g + 1];
  if (s0 >= s1) return;

  __shared__ __align__(16) unsigned short Kh[2][64*64], Kl[2][64*64];  // 32 KB
  __shared__ __align__(16) unsigned short Qh[2][32*64], Ql[2][32*64];  // 16 KB
  __shared__ float S_lds[LL][33];                                       // 8.25 KB
  __shared__ float bias_lds[LL];

  if (t < LL) bias_lds[t] = __expf(50.0f * (1.0f - msk[g * LL + t])) - 1.0f;

  for (int cs = s0; cs < s1; cs += 32) {
    int qc = min(32, s1 - cs);
    f32x4 acc[2];
    acc[0] = (f32x4){0.f,0.f,0.f,0.f};
    acc[1] = (f32x4){0.f,0.f,0.f,0.f};

    for (int kt = 0; kt < 4; ++kt) {
      int k0 = h * 256 + kt * 64;
      __syncthreads();
      // stage K 64x64 fp32 tile for this half -> split hi/lo
      #pragma unroll
      for (int i = 0; i < 4; ++i) {
        int idx = i * 256 + th, r = idx >> 4, c4 = idx & 15;
        float4 v = *(const float4*)&kk_[((size_t)g * LL + r) * DD + k0 + c4 * 4];
        split_store(Kh[h], Kl[h], r, c4, v);
      }
      // stage qt tiles (pre-split in global): 32 rows x 8 slots = 256, one/thread
      {
        int r = th >> 3, s = th & 7;
        uint4 vh = make_uint4(0,0,0,0), vl = make_uint4(0,0,0,0);
        if (r < qc) {
          vh = *(const uint4*)&qt_h[(size_t)(cs + r) * DD + k0 + s * 8];
          vl = *(const uint4*)&qt_l[(size_t)(cs + r) * DD + k0 + s * 8];
        }
        int slot = r * 8 + (s ^ (r & 7));
        ((uint4*)Qh[h])[slot] = vh;
        ((uint4*)Ql[h])[slot] = vl;
      }
      __syncthreads();
      #pragma unroll
      for (int kk = 0; kk < 2; ++kk) {
        int sl = kk * 4 + (lane >> 4);
        int rA = wl * 16 + (lane & 15);
        short8v aH = frag(Kh[h], rA, sl), aL = frag(Kl[h], rA, sl);
        #pragma unroll
        for (int fn = 0; fn < 2; ++fn) {
          int rB = fn * 16 + (lane & 15);
          short8v bH = frag(Qh[h], rB, sl), bL = frag(Ql[h], rB, sl);
          acc[fn] = __builtin_amdgcn_mfma_f32_16x16x32_bf16(aH, bH, acc[fn], 0, 0, 0);
          acc[fn] = __builtin_amdgcn_mfma_f32_16x16x32_bf16(aH, bL, acc[fn], 0, 0, 0);
          acc[fn] = __builtin_amdgcn_mfma_f32_16x16x32_bf16(aL, bH, acc[fn], 0, 0, 0);
        }
      }
    }
    // combine halves: half0 stores partial, half1 adds + scales + biases
    {
      int cq = lane & 15, rq = lane >> 4;
      if (h == 0) {
        #pragma unroll
        for (int fn = 0; fn < 2; ++fn)
          #pragma unroll
          for (int j = 0; j < 4; ++j)
            S_lds[wl * 16 + rq * 4 + j][fn * 16 + cq] = acc[fn][j];
      }
      __syncthreads();
      if (h == 1) {
        #pragma unroll
        for (int fn = 0; fn < 2; ++fn)
          #pragma unroll
          for (int j = 0; j < 4; ++j) {
            int l = wl * 16 + rq * 4 + j, qq = fn * 16 + cq;
            S_lds[l][qq] = (S_lds[l][qq] + acc[fn][j]) * 0.044194173824159216f - bias_lds[l];
          }
      }
    }
    __syncthreads();
    // softmax over l: 16 lanes per query (512 threads = 32 q x 16 lanes)
    {
      int q = t >> 4, i = t & 15;
      float sv0 = S_lds[i][q], sv1 = S_lds[i + 16][q];
      float sv2 = S_lds[i + 32][q], sv3 = S_lds[i + 48][q];
      float mx = fmaxf(fmaxf(sv0, sv1), fmaxf(sv2, sv3));
      #pragma unroll
      for (int off = 1; off < 16; off <<= 1) mx = fmaxf(mx, __shfl_xor(mx, off, 16));
      float e0 = __expf(sv0 - mx), e1 = __expf(sv1 - mx);
      float e2 = __expf(sv2 - mx), e3 = __expf(sv3 - mx);
      float sum = e0 + e1 + e2 + e3;
      #pragma unroll
      for (int off = 1; off < 16; off <<= 1) sum += __shfl_xor(sum, off, 16);
      float inv = 1.0f / sum;
      if (q < qc) {
        float* ap = a_out + (size_t)(cs + q) * LL;
        ap[i]      = e0 * inv;
        ap[i + 16] = e1 * inv;
        ap[i + 32] = e2 * inv;
        ap[i + 48] = e3 * inv;
      }
    }
    __syncthreads();
  }
}

// ---------------- PV: out[n][d] = sum_l a[n][l] * v[g][l][d] ----------------
__global__ __launch_bounds__(256) void k_pv(
    const float* __restrict__ a_in, const float* __restrict__ vv_,
    const int* __restrict__ starts, float* __restrict__ out) {
  int g = blockIdx.x >> 2, dq = blockIdx.x & 3;
  int t = threadIdx.x;
  int s0 = starts[g], s1 = starts[g + 1];
  if (s0 >= s1) return;

  __shared__ __align__(16) float al[LL][17];

  int d4 = t & 31, qh = t >> 5;
  const float* vb = vv_ + (size_t)g * LL * DD + dq * 128 + d4 * 4;

  for (int cs = s0; cs < s1; cs += 16) {
    int qc = min(16, s1 - cs);
    __syncthreads();
    {
      int q = t >> 4, l4 = t & 15;
      int row = min(cs + q, NQ - 1);
      float4 av = *(const float4*)&a_in[(size_t)row * LL + l4 * 4];
      al[l4 * 4 + 0][q] = av.x; al[l4 * 4 + 1][q] = av.y;
      al[l4 * 4 + 2][q] = av.z; al[l4 * 4 + 3][q] = av.w;
    }
    __syncthreads();
    float o0[4] = {0.f,0.f,0.f,0.f}, o1[4] = {0.f,0.f,0.f,0.f};
    #pragma unroll 8
    for (int l = 0; l < LL; ++l) {
      float4 vv = *(const float4*)&vb[(size_t)l * DD];
      float a0 = al[l][qh * 2], a1 = al[l][qh * 2 + 1];
      o0[0] += a0 * vv.x; o0[1] += a0 * vv.y; o0[2] += a0 * vv.z; o0[3] += a0 * vv.w;
      o1[0] += a1 * vv.x; o1[1] += a1 * vv.y; o1[2] += a1 * vv.z; o1[3] += a1 * vv.w;
    }
    int q0 = qh * 2, q1 = qh * 2 + 1;
    if (q0 < qc)
      *(float4*)&out[(size_t)(cs + q0) * DD + dq * 128 + d4 * 4] =
          make_float4(o0[0], o0[1], o0[2], o0[3]);
    if (q1 < qc)
      *(float4*)&out[(size_t)(cs + q1) * DD + dq * 128 + d4 * 4] =
          make_float4(o1[0], o1[1], o1[2], o1[3]);
  }
}

extern "C" void kernel_launch(void* const* d_in, const int* in_sizes, int n_in,
                              void* d_out, int out_size, void* d_ws, size_t ws_size,
                              hipStream_t stream) {
  const float* q_in = (const float*)d_in[0];
  const float* k_in = (const float*)d_in[1];
  const float* v_in = (const float*)d_in[2];
  const float* m_in = (const float*)d_in[3];
  const int*   gid  = (const int*)d_in[4];
  const float* Wq   = (const float*)d_in[5];
  const float* bq   = (const float*)d_in[6];
  const float* Wk   = (const float*)d_in[7];
  // d_in[8] = bk: per-query constant on all scores -> cancels in softmax.
  float* out = (float*)d_out;

  // ws carve: w2t_h[1MB] | w2t_l[1MB] | qt_h[4MB] | qt_l[4MB] | qbf[8MB] |
  //           b2 | starts.  a[1MB] aliases w2t_h (dead after gemm_qt_mfma).
  unsigned short* w2t_h = (unsigned short*)d_ws;
  unsigned short* w2t_l = w2t_h + 512 * 1024;
  unsigned short* qt_h  = w2t_l + 512 * 1024;
  unsigned short* qt_l  = qt_h + 4096 * 512;
  unsigned short* qbf   = qt_l + 4096 * 512;
  float* b2 = (float*)(qbf + 4096 * 1024);
  int* starts = (int*)(b2 + 512);
  float* a = (float*)d_ws;  // alias w2t_h region

  k_starts<<<2, 256, 0, stream>>>(gid, starts);
  k_b2<<<2, 256, 0, stream>>>(Wk, bq, b2);
  k_qbf<<<4096 * 1024 / 8 / 256, 256, 0, stream>>>(q_in, qbf);
  gemm_w2t_mfma<<<dim3(16, 8), 256, 0, stream>>>(Wk, Wq, w2t_h, w2t_l);
  gemm_qt_mfma<<<dim3(8, 64), 256, 0, stream>>>(qbf, w2t_h, w2t_l, b2, qt_h, qt_l);
  k_scores_mfma<<<NGRP, 512, 0, stream>>>(qt_h, qt_l, k_in, m_in, starts, a);
  k_pv<<<NGRP * 4, 256, 0, stream>>>(a, v_in, starts, out);
}

// Round 6
// 89.670 us; speedup vs baseline: 2.6889x; 1.2574x over previous
//
#include <hip/hip_runtime.h>

#define NQ   4096
#define NGRP 256
#define LL   64
#define DD   512

typedef __attribute__((ext_vector_type(8))) short short8v;
typedef __attribute__((ext_vector_type(4))) float f32x4;
typedef __attribute__((ext_vector_type(4))) unsigned short us4v;

// float -> bf16 bits, round-to-nearest-even
static __device__ __forceinline__ unsigned short f2bf(float f) {
  union { float f; unsigned u; } x{f};
  unsigned r = x.u + 0x7fffu + ((x.u >> 16) & 1u);
  return (unsigned short)(r >> 16);
}
static __device__ __forceinline__ float bf2f(unsigned short h) {
  union { unsigned u; float f; } x{(unsigned)h << 16};
  return x.f;
}

// split fp32 float4 -> hi/lo bf16 into XOR-slot-swizzled LDS tile [rows][8 slots of us8]
static __device__ __forceinline__ void split_store(
    unsigned short* Hh, unsigned short* Hl, int r, int c4, float4 v) {
  int s = c4 >> 1, hf = c4 & 1;
  int base = (r * 8 + (s ^ (r & 7))) * 8 + hf * 4;
  unsigned short h0 = f2bf(v.x), h1 = f2bf(v.y), h2 = f2bf(v.z), h3 = f2bf(v.w);
  us4v hv = {h0, h1, h2, h3};
  us4v lv = {f2bf(v.x - bf2f(h0)), f2bf(v.y - bf2f(h1)),
             f2bf(v.z - bf2f(h2)), f2bf(v.w - bf2f(h3))};
  *(us4v*)(Hh + base) = hv;
  *(us4v*)(Hl + base) = lv;
}

// MFMA fragment load from swizzled LDS tile
static __device__ __forceinline__ short8v frag(const unsigned short* P, int r, int sl) {
  return *(const short8v*)(P + (r * 8 + (sl ^ (r & 7))) * 8);
}

// ---------------- merged prep ----------------
// blocks [0,128): W2T = Wk @ Wq^T via 3-term split-bf16 MFMA (critical path, first)
// blocks [128,2176): q fp32 -> bf16
// block 2176: group starts; blocks 2177-2178: b2 = Wk @ bq
__global__ __launch_bounds__(256) void k_prep(
    const float* __restrict__ q_in, const int* __restrict__ gid,
    const float* __restrict__ Wk, const float* __restrict__ Wq,
    const float* __restrict__ bq,
    unsigned short* __restrict__ qbf, int* __restrict__ starts,
    float* __restrict__ b2,
    unsigned short* __restrict__ w2t_h, unsigned short* __restrict__ w2t_l) {
  __shared__ __align__(16) unsigned short lds[4 * 64 * 64];  // 32 KB
  int b = blockIdx.x, t = threadIdx.x;
  if (b < 128) {
    unsigned short* Ah = lds;
    unsigned short* Al = lds + 4096;
    unsigned short* Bh = lds + 8192;
    unsigned short* Bl = lds + 12288;
    int lane = t & 63, wid = t >> 6;
    int wm = wid >> 1, wn = wid & 1;
    int n0 = (b & 15) * 64, m0 = (b >> 4) * 64;
    f32x4 acc[2][2];
    #pragma unroll
    for (int i = 0; i < 2; ++i)
      #pragma unroll
      for (int j = 0; j < 2; ++j) acc[i][j] = (f32x4){0.f,0.f,0.f,0.f};

    for (int k0 = 0; k0 < 512; k0 += 64) {
      __syncthreads();
      #pragma unroll
      for (int i = 0; i < 4; ++i) {
        int idx = i * 256 + t, r = idx >> 4, c4 = idx & 15;
        float4 vA = *(const float4*)&Wk[(size_t)(m0 + r) * 512 + k0 + c4 * 4];
        split_store(Ah, Al, r, c4, vA);
        float4 vB = *(const float4*)&Wq[(size_t)(n0 + r) * 512 + k0 + c4 * 4];
        split_store(Bh, Bl, r, c4, vB);
      }
      __syncthreads();
      #pragma unroll
      for (int kk = 0; kk < 2; ++kk) {
        int sl = kk * 4 + (lane >> 4);
        short8v aH[2], aL[2], bH[2], bL[2];
        #pragma unroll
        for (int fm = 0; fm < 2; ++fm) {
          int r = wm * 32 + fm * 16 + (lane & 15);
          aH[fm] = frag(Ah, r, sl); aL[fm] = frag(Al, r, sl);
        }
        #pragma unroll
        for (int fn = 0; fn < 2; ++fn) {
          int r = wn * 32 + fn * 16 + (lane & 15);
          bH[fn] = frag(Bh, r, sl); bL[fn] = frag(Bl, r, sl);
        }
        #pragma unroll
        for (int fm = 0; fm < 2; ++fm)
          #pragma unroll
          for (int fn = 0; fn < 2; ++fn) {
            acc[fm][fn] = __builtin_amdgcn_mfma_f32_16x16x32_bf16(aH[fm], bH[fn], acc[fm][fn], 0, 0, 0);
            acc[fm][fn] = __builtin_amdgcn_mfma_f32_16x16x32_bf16(aH[fm], bL[fn], acc[fm][fn], 0, 0, 0);
            acc[fm][fn] = __builtin_amdgcn_mfma_f32_16x16x32_bf16(aL[fm], bH[fn], acc[fm][fn], 0, 0, 0);
          }
      }
    }
    int cn = lane & 15, rq = lane >> 4;
    #pragma unroll
    for (int fm = 0; fm < 2; ++fm)
      #pragma unroll
      for (int fn = 0; fn < 2; ++fn)
        #pragma unroll
        for (int j = 0; j < 4; ++j) {
          int m = m0 + wm * 32 + fm * 16 + rq * 4 + j;
          int n = n0 + wn * 32 + fn * 16 + cn;
          float c = acc[fm][fn][j];
          unsigned short hi = f2bf(c);
          unsigned short lo = f2bf(c - bf2f(hi));
          size_t off = (size_t)m * 1024 + n;
          w2t_h[off] = hi; w2t_l[off] = lo;
        }
  } else if (b < 2176) {
    int idx = (b - 128) * 256 + t;   // one uint4 (8 bf16) per thread
    const float* src = q_in + (size_t)idx * 8;
    float4 f0 = *(const float4*)src;
    float4 f1 = *(const float4*)(src + 4);
    uint4 pk;
    pk.x = (unsigned)f2bf(f0.x) | ((unsigned)f2bf(f0.y) << 16);
    pk.y = (unsigned)f2bf(f0.z) | ((unsigned)f2bf(f0.w) << 16);
    pk.z = (unsigned)f2bf(f1.x) | ((unsigned)f2bf(f1.y) << 16);
    pk.w = (unsigned)f2bf(f1.z) | ((unsigned)f2bf(f1.w) << 16);
    ((uint4*)qbf)[idx] = pk;
  } else if (b == 2176) {
    for (int g = t; g <= NGRP; g += 256) {
      int lo = 0, hi = NQ;
      while (lo < hi) { int mid = (lo + hi) >> 1; if (gid[mid] < g) lo = mid + 1; else hi = mid; }
      starts[g] = lo;
    }
  } else {
    int dd = (b - 2177) * 256 + t;
    if (dd < DD) {
      float s = 0.f;
      const float* row = Wk + (size_t)dd * DD;
      for (int j = 0; j < DD; j += 4) {
        float4 w = *(const float4*)&row[j];
        float4 bb = *(const float4*)&bq[j];
        s += w.x*bb.x + w.y*bb.y + w.z*bb.z + w.w*bb.w;
      }
      b2[dd] = s;
    }
  }
}

// ---------------- qt = q @ W2 + b2 via split-bf16 MFMA ----------------
// BM=BN=BK=64, grid (8, 64) = 512 blocks. A = qbf (bf16). Emits qt split hi/lo.
__global__ __launch_bounds__(256) void gemm_qt_mfma(
    const unsigned short* __restrict__ qbf,
    const unsigned short* __restrict__ w2t_h,
    const unsigned short* __restrict__ w2t_l,
    const float* __restrict__ b2,
    unsigned short* __restrict__ qt_h, unsigned short* __restrict__ qt_l) {
  __shared__ __align__(16) unsigned short As[64 * 64];
  __shared__ __align__(16) unsigned short Bh[64 * 64];
  __shared__ __align__(16) unsigned short Bl[64 * 64];
  int t = threadIdx.x;
  int lane = t & 63, wid = t >> 6;
  int wm = wid >> 1, wn = wid & 1;
  int n0 = blockIdx.x * 64, m0 = blockIdx.y * 64;

  f32x4 acc[2][2];
  #pragma unroll
  for (int i = 0; i < 2; ++i)
    #pragma unroll
    for (int j = 0; j < 2; ++j) acc[i][j] = (f32x4){0.f, 0.f, 0.f, 0.f};

  for (int k0 = 0; k0 < 1024; k0 += 64) {
    __syncthreads();
    #pragma unroll
    for (int i = 0; i < 2; ++i) {
      int idx = i * 256 + t;
      int r = idx >> 3, s = idx & 7;
      int dst = r * 8 + (s ^ (r & 7));
      ((uint4*)As)[dst] = *(const uint4*)(qbf + (size_t)(m0 + r) * 1024 + k0 + s * 8);
    }
    #pragma unroll
    for (int i = 0; i < 2; ++i) {
      int idx = i * 256 + t;
      int r = idx >> 3, s = idx & 7;
      int dst = r * 8 + (s ^ (r & 7));
      ((uint4*)Bh)[dst] = *(const uint4*)(w2t_h + (size_t)(n0 + r) * 1024 + k0 + s * 8);
      ((uint4*)Bl)[dst] = *(const uint4*)(w2t_l + (size_t)(n0 + r) * 1024 + k0 + s * 8);
    }
    __syncthreads();
    #pragma unroll
    for (int kk = 0; kk < 2; ++kk) {
      short8v aF[2], bHF[2], bLF[2];
      int sl = kk * 4 + (lane >> 4);
      #pragma unroll
      for (int fm = 0; fm < 2; ++fm)
        aF[fm] = frag(As, wm * 32 + fm * 16 + (lane & 15), sl);
      #pragma unroll
      for (int fn = 0; fn < 2; ++fn) {
        int r = wn * 32 + fn * 16 + (lane & 15);
        bHF[fn] = frag(Bh, r, sl);
        bLF[fn] = frag(Bl, r, sl);
      }
      #pragma unroll
      for (int fm = 0; fm < 2; ++fm)
        #pragma unroll
        for (int fn = 0; fn < 2; ++fn) {
          acc[fm][fn] = __builtin_amdgcn_mfma_f32_16x16x32_bf16(aF[fm], bHF[fn], acc[fm][fn], 0, 0, 0);
          acc[fm][fn] = __builtin_amdgcn_mfma_f32_16x16x32_bf16(aF[fm], bLF[fn], acc[fm][fn], 0, 0, 0);
        }
    }
  }
  int cn = lane & 15, rq = lane >> 4;
  #pragma unroll
  for (int fn = 0; fn < 2; ++fn) {
    int n = n0 + wn * 32 + fn * 16 + cn;
    float bias = b2[n];
    #pragma unroll
    for (int fm = 0; fm < 2; ++fm)
      #pragma unroll
      for (int j = 0; j < 4; ++j) {
        int m = m0 + wm * 32 + fm * 16 + rq * 4 + j;
        float val = acc[fm][fn][j] + bias;
        unsigned short hi = f2bf(val);
        unsigned short lo = f2bf(val - bf2f(hi));
        qt_h[(size_t)m * 512 + n] = hi;
        qt_l[(size_t)m * 512 + n] = lo;
      }
  }
}

// ---------------- fused attention: scores (split-D MFMA) + softmax + PV --------
// One block per group, 512 threads = 8 waves. Scores: waves 0-3 d[0,256),
// waves 4-7 d[256,512), 3-term split bf16, combine in LDS. Softmax in-place.
// PV: wave w -> queries 4w..4w+3; lane -> 8 d's; a via broadcast ds_read_b128.
__global__ __launch_bounds__(512) void k_attn(
    const unsigned short* __restrict__ qt_h, const unsigned short* __restrict__ qt_l,
    const float* __restrict__ kk_, const float* __restrict__ vv_,
    const float* __restrict__ msk, const int* __restrict__ starts,
    float* __restrict__ out) {
  int g = blockIdx.x;
  int t = threadIdx.x, lane = t & 63, wid = t >> 6;
  int h = wid >> 2;        // d-half
  int wl = wid & 3;        // l-tile
  int th = t & 255;        // thread-in-half
  int s0 = starts[g], s1 = starts[g + 1];
  if (s0 >= s1) return;

  __shared__ __align__(16) unsigned short Kh[2][64*64], Kl[2][64*64];  // 32 KB
  __shared__ __align__(16) unsigned short Qh[2][32*64], Ql[2][32*64];  // 16 KB
  __shared__ __align__(16) float S_lds[LL][36];                         // 9 KB
  __shared__ float bias_lds[LL];

  if (t < LL) bias_lds[t] = __expf(50.0f * (1.0f - msk[g * LL + t])) - 1.0f;

  for (int cs = s0; cs < s1; cs += 32) {
    int qc = min(32, s1 - cs);
    f32x4 acc[2];
    acc[0] = (f32x4){0.f,0.f,0.f,0.f};
    acc[1] = (f32x4){0.f,0.f,0.f,0.f};

    for (int kt = 0; kt < 4; ++kt) {
      int k0 = h * 256 + kt * 64;
      __syncthreads();
      #pragma unroll
      for (int i = 0; i < 4; ++i) {
        int idx = i * 256 + th, r = idx >> 4, c4 = idx & 15;
        float4 v = *(const float4*)&kk_[((size_t)g * LL + r) * DD + k0 + c4 * 4];
        split_store(Kh[h], Kl[h], r, c4, v);
      }
      {
        int r = th >> 3, s = th & 7;
        uint4 vh = make_uint4(0,0,0,0), vl = make_uint4(0,0,0,0);
        if (r < qc) {
          vh = *(const uint4*)&qt_h[(size_t)(cs + r) * DD + k0 + s * 8];
          vl = *(const uint4*)&qt_l[(size_t)(cs + r) * DD + k0 + s * 8];
        }
        int slot = r * 8 + (s ^ (r & 7));
        ((uint4*)Qh[h])[slot] = vh;
        ((uint4*)Ql[h])[slot] = vl;
      }
      __syncthreads();
      #pragma unroll
      for (int kk = 0; kk < 2; ++kk) {
        int sl = kk * 4 + (lane >> 4);
        int rA = wl * 16 + (lane & 15);
        short8v aH = frag(Kh[h], rA, sl), aL = frag(Kl[h], rA, sl);
        #pragma unroll
        for (int fn = 0; fn < 2; ++fn) {
          int rB = fn * 16 + (lane & 15);
          short8v bH = frag(Qh[h], rB, sl), bL = frag(Ql[h], rB, sl);
          acc[fn] = __builtin_amdgcn_mfma_f32_16x16x32_bf16(aH, bH, acc[fn], 0, 0, 0);
          acc[fn] = __builtin_amdgcn_mfma_f32_16x16x32_bf16(aH, bL, acc[fn], 0, 0, 0);
          acc[fn] = __builtin_amdgcn_mfma_f32_16x16x32_bf16(aL, bH, acc[fn], 0, 0, 0);
        }
      }
    }
    // combine halves: half0 stores partial, half1 adds + scales + biases
    {
      int cq = lane & 15, rq = lane >> 4;
      if (h == 0) {
        #pragma unroll
        for (int fn = 0; fn < 2; ++fn)
          #pragma unroll
          for (int j = 0; j < 4; ++j)
            S_lds[wl * 16 + rq * 4 + j][fn * 16 + cq] = acc[fn][j];
      }
      __syncthreads();
      if (h == 1) {
        #pragma unroll
        for (int fn = 0; fn < 2; ++fn)
          #pragma unroll
          for (int j = 0; j < 4; ++j) {
            int l = wl * 16 + rq * 4 + j, qq = fn * 16 + cq;
            S_lds[l][qq] = (S_lds[l][qq] + acc[fn][j]) * 0.044194173824159216f - bias_lds[l];
          }
      }
    }
    __syncthreads();
    // softmax over l, in place: 16 lanes per query (512 threads = 32 q)
    {
      int q = t >> 4, i = t & 15;
      float sv0 = S_lds[i][q], sv1 = S_lds[i + 16][q];
      float sv2 = S_lds[i + 32][q], sv3 = S_lds[i + 48][q];
      float mx = fmaxf(fmaxf(sv0, sv1), fmaxf(sv2, sv3));
      #pragma unroll
      for (int off = 1; off < 16; off <<= 1) mx = fmaxf(mx, __shfl_xor(mx, off, 16));
      float e0 = __expf(sv0 - mx), e1 = __expf(sv1 - mx);
      float e2 = __expf(sv2 - mx), e3 = __expf(sv3 - mx);
      float sum = e0 + e1 + e2 + e3;
      #pragma unroll
      for (int off = 1; off < 16; off <<= 1) sum += __shfl_xor(sum, off, 16);
      float inv = 1.0f / sum;
      S_lds[i][q]      = e0 * inv;
      S_lds[i + 16][q] = e1 * inv;
      S_lds[i + 32][q] = e2 * inv;
      S_lds[i + 48][q] = e3 * inv;
    }
    __syncthreads();
    // PV: wave wid -> queries 4*wid..4*wid+3; lane -> d = lane*8..lane*8+7
    {
      float o[4][8];
      #pragma unroll
      for (int u = 0; u < 4; ++u)
        #pragma unroll
        for (int d = 0; d < 8; ++d) o[u][d] = 0.f;
      const float* vb = vv_ + (size_t)g * LL * DD + lane * 8;
      #pragma unroll 4
      for (int l = 0; l < LL; ++l) {
        float4 v0 = *(const float4*)&vb[(size_t)l * DD];
        float4 v1 = *(const float4*)&vb[(size_t)l * DD + 4];
        float4 aa = *(const float4*)&S_lds[l][wid * 4];
        float av[4] = {aa.x, aa.y, aa.z, aa.w};
        #pragma unroll
        for (int u = 0; u < 4; ++u) {
          o[u][0] += av[u]*v0.x; o[u][1] += av[u]*v0.y;
          o[u][2] += av[u]*v0.z; o[u][3] += av[u]*v0.w;
          o[u][4] += av[u]*v1.x; o[u][5] += av[u]*v1.y;
          o[u][6] += av[u]*v1.z; o[u][7] += av[u]*v1.w;
        }
      }
      #pragma unroll
      for (int u = 0; u < 4; ++u) {
        int q = wid * 4 + u;
        if (q < qc) {
          float* op = out + (size_t)(cs + q) * DD + lane * 8;
          *(float4*)op       = make_float4(o[u][0], o[u][1], o[u][2], o[u][3]);
          *(float4*)(op + 4) = make_float4(o[u][4], o[u][5], o[u][6], o[u][7]);
        }
      }
    }
    __syncthreads();
  }
}

extern "C" void kernel_launch(void* const* d_in, const int* in_sizes, int n_in,
                              void* d_out, int out_size, void* d_ws, size_t ws_size,
                              hipStream_t stream) {
  const float* q_in = (const float*)d_in[0];
  const float* k_in = (const float*)d_in[1];
  const float* v_in = (const float*)d_in[2];
  const float* m_in = (const float*)d_in[3];
  const int*   gid  = (const int*)d_in[4];
  const float* Wq   = (const float*)d_in[5];
  const float* bq   = (const float*)d_in[6];
  const float* Wk   = (const float*)d_in[7];
  // d_in[8] = bk: per-query constant on all scores -> cancels in softmax.
  float* out = (float*)d_out;

  // ws carve: w2t_h[1MB] | w2t_l[1MB] | qt_h[4MB] | qt_l[4MB] | qbf[8MB] | b2 | starts
  unsigned short* w2t_h = (unsigned short*)d_ws;
  unsigned short* w2t_l = w2t_h + 512 * 1024;
  unsigned short* qt_h  = w2t_l + 512 * 1024;
  unsigned short* qt_l  = qt_h + 4096 * 512;
  unsigned short* qbf   = qt_l + 4096 * 512;
  float* b2 = (float*)(qbf + 4096 * 1024);
  int* starts = (int*)(b2 + 512);

  // 1) prep: w2t (blocks 0-127) + qbf (128-2175) + starts (2176) + b2 (2177-2178)
  k_prep<<<2179, 256, 0, stream>>>(q_in, gid, Wk, Wq, bq, qbf, starts, b2, w2t_h, w2t_l);
  // 2) qt = q @ W2 + b2 (split bf16 out)
  gemm_qt_mfma<<<dim3(8, 64), 256, 0, stream>>>(qbf, w2t_h, w2t_l, b2, qt_h, qt_l);
  // 3) fused scores + softmax + PV
  k_attn<<<NGRP, 512, 0, stream>>>(qt_h, qt_l, k_in, v_in, m_in, starts, out);
}

// Round 7
// 70.272 us; speedup vs baseline: 3.4311x; 1.2760x over previous
//
#include <hip/hip_runtime.h>

#define NQ   4096
#define NGRP 256
#define LL   64
#define DD   512

typedef __attribute__((ext_vector_type(8))) short short8v;
typedef __attribute__((ext_vector_type(4))) float f32x4;
typedef __attribute__((ext_vector_type(4))) unsigned short us4v;

#define SCALE 0.044194173824159216f

// float -> bf16 bits, round-to-nearest-even
static __device__ __forceinline__ unsigned short f2bf(float f) {
  union { float f; unsigned u; } x{f};
  unsigned r = x.u + 0x7fffu + ((x.u >> 16) & 1u);
  return (unsigned short)(r >> 16);
}
static __device__ __forceinline__ float bf2f(unsigned short h) {
  union { unsigned u; float f; } x{(unsigned)h << 16};
  return x.f;
}

// split fp32 float4 -> hi/lo bf16 into XOR-slot-swizzled LDS tile [rows][8 slots of us8]
static __device__ __forceinline__ void split_store(
    unsigned short* Hh, unsigned short* Hl, int r, int c4, float4 v) {
  int s = c4 >> 1, hf = c4 & 1;
  int base = (r * 8 + (s ^ (r & 7))) * 8 + hf * 4;
  unsigned short h0 = f2bf(v.x), h1 = f2bf(v.y), h2 = f2bf(v.z), h3 = f2bf(v.w);
  us4v hv = {h0, h1, h2, h3};
  us4v lv = {f2bf(v.x - bf2f(h0)), f2bf(v.y - bf2f(h1)),
             f2bf(v.z - bf2f(h2)), f2bf(v.w - bf2f(h3))};
  *(us4v*)(Hh + base) = hv;
  *(us4v*)(Hl + base) = lv;
}

// MFMA fragment load from swizzled LDS tile
static __device__ __forceinline__ short8v frag(const unsigned short* P, int r, int sl) {
  return *(const short8v*)(P + (r * 8 + (sl ^ (r & 7))) * 8);
}

// ---------------- merged prep ----------------
// blocks [0,128): W2T = Wk @ Wq^T via 3-term split-bf16 MFMA
// blocks [128,2176): q fp32 -> bf16;  2176: starts;  2177-2178: b2 = Wk @ bq
__global__ __launch_bounds__(256) void k_prep(
    const float* __restrict__ q_in, const int* __restrict__ gid,
    const float* __restrict__ Wk, const float* __restrict__ Wq,
    const float* __restrict__ bq,
    unsigned short* __restrict__ qbf, int* __restrict__ starts,
    float* __restrict__ b2,
    unsigned short* __restrict__ w2t_h, unsigned short* __restrict__ w2t_l) {
  __shared__ __align__(16) unsigned short lds[4 * 64 * 64];  // 32 KB
  int b = blockIdx.x, t = threadIdx.x;
  if (b < 128) {
    unsigned short* Ah = lds;
    unsigned short* Al = lds + 4096;
    unsigned short* Bh = lds + 8192;
    unsigned short* Bl = lds + 12288;
    int lane = t & 63, wid = t >> 6;
    int wm = wid >> 1, wn = wid & 1;
    int n0 = (b & 15) * 64, m0 = (b >> 4) * 64;
    f32x4 acc[2][2];
    #pragma unroll
    for (int i = 0; i < 2; ++i)
      #pragma unroll
      for (int j = 0; j < 2; ++j) acc[i][j] = (f32x4){0.f,0.f,0.f,0.f};

    for (int k0 = 0; k0 < 512; k0 += 64) {
      __syncthreads();
      #pragma unroll
      for (int i = 0; i < 4; ++i) {
        int idx = i * 256 + t, r = idx >> 4, c4 = idx & 15;
        float4 vA = *(const float4*)&Wk[(size_t)(m0 + r) * 512 + k0 + c4 * 4];
        split_store(Ah, Al, r, c4, vA);
        float4 vB = *(const float4*)&Wq[(size_t)(n0 + r) * 512 + k0 + c4 * 4];
        split_store(Bh, Bl, r, c4, vB);
      }
      __syncthreads();
      #pragma unroll
      for (int kk = 0; kk < 2; ++kk) {
        int sl = kk * 4 + (lane >> 4);
        short8v aH[2], aL[2], bH[2], bL[2];
        #pragma unroll
        for (int fm = 0; fm < 2; ++fm) {
          int r = wm * 32 + fm * 16 + (lane & 15);
          aH[fm] = frag(Ah, r, sl); aL[fm] = frag(Al, r, sl);
        }
        #pragma unroll
        for (int fn = 0; fn < 2; ++fn) {
          int r = wn * 32 + fn * 16 + (lane & 15);
          bH[fn] = frag(Bh, r, sl); bL[fn] = frag(Bl, r, sl);
        }
        #pragma unroll
        for (int fm = 0; fm < 2; ++fm)
          #pragma unroll
          for (int fn = 0; fn < 2; ++fn) {
            acc[fm][fn] = __builtin_amdgcn_mfma_f32_16x16x32_bf16(aH[fm], bH[fn], acc[fm][fn], 0, 0, 0);
            acc[fm][fn] = __builtin_amdgcn_mfma_f32_16x16x32_bf16(aH[fm], bL[fn], acc[fm][fn], 0, 0, 0);
            acc[fm][fn] = __builtin_amdgcn_mfma_f32_16x16x32_bf16(aL[fm], bH[fn], acc[fm][fn], 0, 0, 0);
          }
      }
    }
    int cn = lane & 15, rq = lane >> 4;
    #pragma unroll
    for (int fm = 0; fm < 2; ++fm)
      #pragma unroll
      for (int fn = 0; fn < 2; ++fn)
        #pragma unroll
        for (int j = 0; j < 4; ++j) {
          int m = m0 + wm * 32 + fm * 16 + rq * 4 + j;
          int n = n0 + wn * 32 + fn * 16 + cn;
          float c = acc[fm][fn][j];
          unsigned short hi = f2bf(c);
          unsigned short lo = f2bf(c - bf2f(hi));
          size_t off = (size_t)m * 1024 + n;
          w2t_h[off] = hi; w2t_l[off] = lo;
        }
  } else if (b < 2176) {
    int idx = (b - 128) * 256 + t;   // one uint4 (8 bf16) per thread
    const float* src = q_in + (size_t)idx * 8;
    float4 f0 = *(const float4*)src;
    float4 f1 = *(const float4*)(src + 4);
    uint4 pk;
    pk.x = (unsigned)f2bf(f0.x) | ((unsigned)f2bf(f0.y) << 16);
    pk.y = (unsigned)f2bf(f0.z) | ((unsigned)f2bf(f0.w) << 16);
    pk.z = (unsigned)f2bf(f1.x) | ((unsigned)f2bf(f1.y) << 16);
    pk.w = (unsigned)f2bf(f1.z) | ((unsigned)f2bf(f1.w) << 16);
    ((uint4*)qbf)[idx] = pk;
  } else if (b == 2176) {
    for (int g = t; g <= NGRP; g += 256) {
      int lo = 0, hi = NQ;
      while (lo < hi) { int mid = (lo + hi) >> 1; if (gid[mid] < g) lo = mid + 1; else hi = mid; }
      starts[g] = lo;
    }
  } else {
    int dd = (b - 2177) * 256 + t;
    if (dd < DD) {
      float s = 0.f;
      const float* row = Wk + (size_t)dd * DD;
      for (int j = 0; j < DD; j += 4) {
        float4 w = *(const float4*)&row[j];
        float4 bb = *(const float4*)&bq[j];
        s += w.x*bb.x + w.y*bb.y + w.z*bb.z + w.w*bb.w;
      }
      b2[dd] = s;
    }
  }
}

// ---------------- qt = q @ W2 + b2 via split-bf16 MFMA ----------------
__global__ __launch_bounds__(256) void gemm_qt_mfma(
    const unsigned short* __restrict__ qbf,
    const unsigned short* __restrict__ w2t_h,
    const unsigned short* __restrict__ w2t_l,
    const float* __restrict__ b2,
    unsigned short* __restrict__ qt_h, unsigned short* __restrict__ qt_l) {
  __shared__ __align__(16) unsigned short As[64 * 64];
  __shared__ __align__(16) unsigned short Bh[64 * 64];
  __shared__ __align__(16) unsigned short Bl[64 * 64];
  int t = threadIdx.x;
  int lane = t & 63, wid = t >> 6;
  int wm = wid >> 1, wn = wid & 1;
  int n0 = blockIdx.x * 64, m0 = blockIdx.y * 64;

  f32x4 acc[2][2];
  #pragma unroll
  for (int i = 0; i < 2; ++i)
    #pragma unroll
    for (int j = 0; j < 2; ++j) acc[i][j] = (f32x4){0.f, 0.f, 0.f, 0.f};

  for (int k0 = 0; k0 < 1024; k0 += 64) {
    __syncthreads();
    #pragma unroll
    for (int i = 0; i < 2; ++i) {
      int idx = i * 256 + t;
      int r = idx >> 3, s = idx & 7;
      int dst = r * 8 + (s ^ (r & 7));
      ((uint4*)As)[dst] = *(const uint4*)(qbf + (size_t)(m0 + r) * 1024 + k0 + s * 8);
    }
    #pragma unroll
    for (int i = 0; i < 2; ++i) {
      int idx = i * 256 + t;
      int r = idx >> 3, s = idx & 7;
      int dst = r * 8 + (s ^ (r & 7));
      ((uint4*)Bh)[dst] = *(const uint4*)(w2t_h + (size_t)(n0 + r) * 1024 + k0 + s * 8);
      ((uint4*)Bl)[dst] = *(const uint4*)(w2t_l + (size_t)(n0 + r) * 1024 + k0 + s * 8);
    }
    __syncthreads();
    #pragma unroll
    for (int kk = 0; kk < 2; ++kk) {
      short8v aF[2], bHF[2], bLF[2];
      int sl = kk * 4 + (lane >> 4);
      #pragma unroll
      for (int fm = 0; fm < 2; ++fm)
        aF[fm] = frag(As, wm * 32 + fm * 16 + (lane & 15), sl);
      #pragma unroll
      for (int fn = 0; fn < 2; ++fn) {
        int r = wn * 32 + fn * 16 + (lane & 15);
        bHF[fn] = frag(Bh, r, sl);
        bLF[fn] = frag(Bl, r, sl);
      }
      #pragma unroll
      for (int fm = 0; fm < 2; ++fm)
        #pragma unroll
        for (int fn = 0; fn < 2; ++fn) {
          acc[fm][fn] = __builtin_amdgcn_mfma_f32_16x16x32_bf16(aF[fm], bHF[fn], acc[fm][fn], 0, 0, 0);
          acc[fm][fn] = __builtin_amdgcn_mfma_f32_16x16x32_bf16(aF[fm], bLF[fn], acc[fm][fn], 0, 0, 0);
        }
    }
  }
  int cn = lane & 15, rq = lane >> 4;
  #pragma unroll
  for (int fn = 0; fn < 2; ++fn) {
    int n = n0 + wn * 32 + fn * 16 + cn;
    float bias = b2[n];
    #pragma unroll
    for (int fm = 0; fm < 2; ++fm)
      #pragma unroll
      for (int j = 0; j < 4; ++j) {
        int m = m0 + wm * 32 + fm * 16 + rq * 4 + j;
        float val = acc[fm][fn][j] + bias;
        unsigned short hi = f2bf(val);
        unsigned short lo = f2bf(val - bf2f(hi));
        qt_h[(size_t)m * 512 + n] = hi;
        qt_l[(size_t)m * 512 + n] = lo;
      }
  }
}

// ---------------- partial scores: S_part[dq][n][l] ----------------
// Grid 1024: g = bx>>2, dq = bx&3 (d-quarter of 128). 256 threads = 4 waves,
// wave wl owns l-tile wl. 2 staged k-tiles per block; 3-term split-bf16 MFMA.
__global__ __launch_bounds__(256) void k_scores4(
    const unsigned short* __restrict__ qt_h, const unsigned short* __restrict__ qt_l,
    const float* __restrict__ kk_, const int* __restrict__ starts,
    float* __restrict__ s_part) {
  int g = blockIdx.x >> 2, dq = blockIdx.x & 3;
  int t = threadIdx.x, lane = t & 63, wl = t >> 6;
  int s0 = starts[g], s1 = starts[g + 1];
  if (s0 >= s1) return;

  __shared__ __align__(16) unsigned short Kh[64*64], Kl[64*64];  // 8 KB each
  __shared__ __align__(16) unsigned short Qh[32*64], Ql[32*64];  // 4 KB each

  float* sp = s_part + (size_t)dq * NQ * LL;

  for (int cs = s0; cs < s1; cs += 32) {
    int qc = min(32, s1 - cs);
    f32x4 acc[2];
    acc[0] = (f32x4){0.f,0.f,0.f,0.f};
    acc[1] = (f32x4){0.f,0.f,0.f,0.f};

    #pragma unroll
    for (int kt = 0; kt < 2; ++kt) {
      int k0 = dq * 128 + kt * 64;
      __syncthreads();
      #pragma unroll
      for (int i = 0; i < 4; ++i) {
        int idx = i * 256 + t, r = idx >> 4, c4 = idx & 15;
        float4 v = *(const float4*)&kk_[((size_t)g * LL + r) * DD + k0 + c4 * 4];
        split_store(Kh, Kl, r, c4, v);
      }
      {
        int r = t >> 3, s = t & 7;
        uint4 vh = make_uint4(0,0,0,0), vl = make_uint4(0,0,0,0);
        if (r < qc) {
          vh = *(const uint4*)&qt_h[(size_t)(cs + r) * DD + k0 + s * 8];
          vl = *(const uint4*)&qt_l[(size_t)(cs + r) * DD + k0 + s * 8];
        }
        int slot = r * 8 + (s ^ (r & 7));
        ((uint4*)Qh)[slot] = vh;
        ((uint4*)Ql)[slot] = vl;
      }
      __syncthreads();
      #pragma unroll
      for (int kk = 0; kk < 2; ++kk) {
        int sl = kk * 4 + (lane >> 4);
        int rA = wl * 16 + (lane & 15);
        short8v aH = frag(Kh, rA, sl), aL = frag(Kl, rA, sl);
        #pragma unroll
        for (int fn = 0; fn < 2; ++fn) {
          int rB = fn * 16 + (lane & 15);
          short8v bH = frag(Qh, rB, sl), bL = frag(Ql, rB, sl);
          acc[fn] = __builtin_amdgcn_mfma_f32_16x16x32_bf16(aH, bH, acc[fn], 0, 0, 0);
          acc[fn] = __builtin_amdgcn_mfma_f32_16x16x32_bf16(aH, bL, acc[fn], 0, 0, 0);
          acc[fn] = __builtin_amdgcn_mfma_f32_16x16x32_bf16(aL, bH, acc[fn], 0, 0, 0);
        }
      }
    }
    // write partial S (row-guarded)
    {
      int cq = lane & 15, rq = lane >> 4;
      #pragma unroll
      for (int fn = 0; fn < 2; ++fn) {
        int q = fn * 16 + cq;
        if (q < qc) {
          float* row = sp + (size_t)(cs + q) * LL;
          #pragma unroll
          for (int j = 0; j < 4; ++j)
            row[wl * 16 + rq * 4 + j] = acc[fn][j];
        }
      }
    }
  }
}

// ---------------- PV: sum partials + softmax + out ----------------
// Grid 512: g = bx>>1, dh = bx&1 (d-half of 256). 256 threads = 4 waves.
// S_lds is [q][l]-major (stride 68) so softmax and PV use vector reads.
__global__ __launch_bounds__(256) void k_pv2(
    const float* __restrict__ s_part, const float* __restrict__ vv_,
    const float* __restrict__ msk, const int* __restrict__ starts,
    float* __restrict__ out) {
  int g = blockIdx.x >> 1, dh = blockIdx.x & 1;
  int t = threadIdx.x, lane = t & 63, wid = t >> 6;
  int s0 = starts[g], s1 = starts[g + 1];
  if (s0 >= s1) return;

  __shared__ __align__(16) float S_lds[32][68];   // 8.7 KB
  __shared__ float bias_lds[LL];
  if (t < LL) bias_lds[t] = __expf(50.0f * (1.0f - msk[g * LL + t])) - 1.0f;

  const float* vb = vv_ + (size_t)g * LL * DD + dh * 256 + lane * 4;

  for (int cs = s0; cs < s1; cs += 32) {
    int qc = min(32, s1 - cs);
    __syncthreads();
    // sum 4 quarters + scale + bias -> S_lds[q][l]
    #pragma unroll
    for (int i = 0; i < 2; ++i) {
      int f = i * 256 + t;
      int q = f >> 4, l4 = f & 15;
      const float* p = s_part + (size_t)(cs + q) * LL + l4 * 4;
      float4 a0 = *(const float4*)p;
      float4 a1 = *(const float4*)(p + (size_t)NQ * LL);
      float4 a2 = *(const float4*)(p + (size_t)2 * NQ * LL);
      float4 a3 = *(const float4*)(p + (size_t)3 * NQ * LL);
      float4 r;
      r.x = (a0.x + a1.x + a2.x + a3.x) * SCALE - bias_lds[l4 * 4 + 0];
      r.y = (a0.y + a1.y + a2.y + a3.y) * SCALE - bias_lds[l4 * 4 + 1];
      r.z = (a0.z + a1.z + a2.z + a3.z) * SCALE - bias_lds[l4 * 4 + 2];
      r.w = (a0.w + a1.w + a2.w + a3.w) * SCALE - bias_lds[l4 * 4 + 3];
      *(float4*)&S_lds[q][l4 * 4] = r;
    }
    __syncthreads();
    // softmax per q over 64 l: 32 q x 8 lanes
    {
      int q = t >> 3, i = t & 7;
      float4 x0 = *(const float4*)&S_lds[q][i * 8];
      float4 x1 = *(const float4*)&S_lds[q][i * 8 + 4];
      float mx = fmaxf(fmaxf(fmaxf(x0.x, x0.y), fmaxf(x0.z, x0.w)),
                       fmaxf(fmaxf(x1.x, x1.y), fmaxf(x1.z, x1.w)));
      #pragma unroll
      for (int off = 1; off < 8; off <<= 1) mx = fmaxf(mx, __shfl_xor(mx, off, 8));
      float e0 = __expf(x0.x - mx), e1 = __expf(x0.y - mx);
      float e2 = __expf(x0.z - mx), e3 = __expf(x0.w - mx);
      float e4 = __expf(x1.x - mx), e5 = __expf(x1.y - mx);
      float e6 = __expf(x1.z - mx), e7 = __expf(x1.w - mx);
      float sum = ((e0 + e1) + (e2 + e3)) + ((e4 + e5) + (e6 + e7));
      #pragma unroll
      for (int off = 1; off < 8; off <<= 1) sum += __shfl_xor(sum, off, 8);
      float inv = 1.0f / sum;
      *(float4*)&S_lds[q][i * 8]     = make_float4(e0 * inv, e1 * inv, e2 * inv, e3 * inv);
      *(float4*)&S_lds[q][i * 8 + 4] = make_float4(e4 * inv, e5 * inv, e6 * inv, e7 * inv);
    }
    __syncthreads();
    // PV: wave wid -> queries wid*8..+7; lane -> d = dh*256 + lane*4..+3
    {
      float o[8][4];
      #pragma unroll
      for (int u = 0; u < 8; ++u)
        #pragma unroll
        for (int e = 0; e < 4; ++e) o[u][e] = 0.f;
      for (int l0 = 0; l0 < LL; l0 += 4) {
        float a_[8][4];
        #pragma unroll
        for (int u = 0; u < 8; ++u) {
          float4 av = *(const float4*)&S_lds[wid * 8 + u][l0];
          a_[u][0] = av.x; a_[u][1] = av.y; a_[u][2] = av.z; a_[u][3] = av.w;
        }
        #pragma unroll
        for (int e = 0; e < 4; ++e) {
          float4 vv = *(const float4*)&vb[(size_t)(l0 + e) * DD];
          #pragma unroll
          for (int u = 0; u < 8; ++u) {
            o[u][0] += a_[u][e] * vv.x;
            o[u][1] += a_[u][e] * vv.y;
            o[u][2] += a_[u][e] * vv.z;
            o[u][3] += a_[u][e] * vv.w;
          }
        }
      }
      #pragma unroll
      for (int u = 0; u < 8; ++u) {
        int q = wid * 8 + u;
        if (q < qc) {
          *(float4*)&out[(size_t)(cs + q) * DD + dh * 256 + lane * 4] =
              make_float4(o[u][0], o[u][1], o[u][2], o[u][3]);
        }
      }
    }
  }
}

extern "C" void kernel_launch(void* const* d_in, const int* in_sizes, int n_in,
                              void* d_out, int out_size, void* d_ws, size_t ws_size,
                              hipStream_t stream) {
  const float* q_in = (const float*)d_in[0];
  const float* k_in = (const float*)d_in[1];
  const float* v_in = (const float*)d_in[2];
  const float* m_in = (const float*)d_in[3];
  const int*   gid  = (const int*)d_in[4];
  const float* Wq   = (const float*)d_in[5];
  const float* bq   = (const float*)d_in[6];
  const float* Wk   = (const float*)d_in[7];
  // d_in[8] = bk: per-query constant on all scores -> cancels in softmax.
  float* out = (float*)d_out;

  // ws: w2t_h[1MB] | w2t_l[1MB] | qt_h[4MB] | qt_l[4MB] | qbf[8MB] | b2 | starts | s_part[4MB]
  unsigned short* w2t_h = (unsigned short*)d_ws;
  unsigned short* w2t_l = w2t_h + 512 * 1024;
  unsigned short* qt_h  = w2t_l + 512 * 1024;
  unsigned short* qt_l  = qt_h + 4096 * 512;
  unsigned short* qbf   = qt_l + 4096 * 512;
  float* b2 = (float*)(qbf + 4096 * 1024);
  int* starts = (int*)(b2 + 512);
  float* s_part = (float*)(starts + 512);   // [4][4096][64]

  // 1) prep: w2t (blocks 0-127) + qbf (128-2175) + starts (2176) + b2 (2177-2178)
  k_prep<<<2179, 256, 0, stream>>>(q_in, gid, Wk, Wq, bq, qbf, starts, b2, w2t_h, w2t_l);
  // 2) qt = q @ W2 + b2 (split bf16 out)
  gemm_qt_mfma<<<dim3(8, 64), 256, 0, stream>>>(qbf, w2t_h, w2t_l, b2, qt_h, qt_l);
  // 3) partial scores, 4-way d-split (1024 blocks)
  k_scores4<<<NGRP * 4, 256, 0, stream>>>(qt_h, qt_l, k_in, starts, s_part);
  // 4) sum + softmax + PV, 2-way d-split (512 blocks)
  k_pv2<<<NGRP * 2, 256, 0, stream>>>(s_part, v_in, m_in, starts, out);
}